// Round 1
// 576.903 us; speedup vs baseline: 1.2142x; 1.2142x over previous
//
#include <hip/hip_runtime.h>
#include <hip/hip_bf16.h>
#include <stdint.h>

#define NB 64
#define NT 256
#define NH 768
#define BK 32

typedef float f32x4 __attribute__((ext_vector_type(4)));
typedef __bf16 bf16x8 __attribute__((ext_vector_type(8)));

static __device__ __forceinline__ uint16_t f2bf(float f) {
  union { float f; uint32_t u; } v; v.f = f;
  uint32_t r = v.u + 0x7FFFu + ((v.u >> 16) & 1u);
  return (uint16_t)(r >> 16);
}
static __device__ __forceinline__ float bf2f(uint16_t h) {
  union { uint32_t u; float f; } v; v.u = ((uint32_t)h) << 16;
  return v.f;
}

// global -> LDS direct DMA, 16B per lane. LDS dest = wave-uniform base + lane*16.
typedef const __attribute__((address_space(1))) uint32_t* gp1_t;
typedef __attribute__((address_space(3))) uint32_t* lp3_t;
static __device__ __forceinline__ void gload_lds16(const uint16_t* g, uint16_t* l) {
  __builtin_amdgcn_global_load_lds((gp1_t)g, (lp3_t)l, 16, 0, 0);
}

// Chunked bijective XCD swizzle (T1): hardware assigns XCD = linear_id % 8.
// Map so each XCD owns a CONTIGUOUS chunk of logical tiles -> neighbor blocks
// sharing an A-panel hit the same (non-coherent) L2. Requires NWG % 8 == 0.
template <int GX, int GY, int GZ>
static __device__ __forceinline__ void xcd_chunk(int& bx, int& by, int& bz) {
  constexpr int NWG = GX * GY * GZ;
  static_assert(NWG % 8 == 0, "chunked swizzle needs nwg%8==0");
  int lin = ((int)blockIdx.z * GY + (int)blockIdx.y) * GX + (int)blockIdx.x;
  int swz = (lin & 7) * (NWG >> 3) + (lin >> 3);
  bx = swz % GX; swz /= GX;
  by = swz % GY; bz = swz / GY;
}

// ---------------------------------------------------------------------------
// m97-structure 128x128 tile product: acc += A(128,K) * B(128,K)^T.
// 4 waves x (4x4) 16x16x32 bf16 MFMA, BK=32, global_load_lds width-16 staging.
static __device__ __forceinline__ void gemm_product(
    const uint16_t* __restrict__ Abase, const uint16_t* __restrict__ Bbase,
    int K, int lda, int ldb,
    uint16_t* __restrict__ As, uint16_t* __restrict__ Bs, f32x4 acc[4][4]) {
  const int tid = threadIdx.x;
  const int wave = tid >> 6, lane = tid & 63;
  const int r = lane & 15, quad = lane >> 4;
  const int wm = wave >> 1, wn = wave & 1;
  // Staging: chunk c = wave (+4) covers LDS rows [c*16, c*16+16); lane L supplies
  // row c*16 + L/4, k-offset (L%4)*8 (matches HW lane*16B linear dest).
  const int st_row = lane >> 2;
  const int st_k = (lane & 3) * 8;
  for (int k0 = 0; k0 < K; k0 += BK) {
    __syncthreads();  // previous iter's frag reads done before overwrite
    {
      const int c0 = wave, c1 = wave + 4;
      gload_lds16(Abase + (long)(c0 * 16 + st_row) * lda + k0 + st_k, &As[c0 * 512]);
      gload_lds16(Abase + (long)(c1 * 16 + st_row) * lda + k0 + st_k, &As[c1 * 512]);
      gload_lds16(Bbase + (long)(c0 * 16 + st_row) * ldb + k0 + st_k, &Bs[c0 * 512]);
      gload_lds16(Bbase + (long)(c1 * 16 + st_row) * ldb + k0 + st_k, &Bs[c1 * 512]);
    }
    __syncthreads();  // staging visible (compiler drains vmcnt before barrier)
    bf16x8 av[4], bv[4];
#pragma unroll
    for (int mi = 0; mi < 4; ++mi)
      av[mi] = *(const bf16x8*)&As[(wm * 64 + mi * 16 + r) * BK + quad * 8];
#pragma unroll
    for (int ni = 0; ni < 4; ++ni)
      bv[ni] = *(const bf16x8*)&Bs[(wn * 64 + ni * 16 + r) * BK + quad * 8];
#pragma unroll
    for (int mi = 0; mi < 4; ++mi)
#pragma unroll
      for (int ni = 0; ni < 4; ++ni)
        acc[mi][ni] = __builtin_amdgcn_mfma_f32_16x16x32_bf16(av[mi], bv[ni], acc[mi][ni], 0, 0, 0);
  }
}

static __device__ __forceinline__ void acc_zero(f32x4 acc[4][4]) {
#pragma unroll
  for (int i = 0; i < 4; ++i)
#pragma unroll
    for (int j = 0; j < 4; ++j) acc[i][j] = (f32x4){0.f, 0.f, 0.f, 0.f};
}

// C/D frag: col = lane&15, row = quad*4 + t   [verified m89/m91]
static __device__ __forceinline__ void frag_rc(int& row0, int& col0) {
  const int lane = threadIdx.x & 63, wave = threadIdx.x >> 6;
  row0 = (wave >> 1) * 64 + (lane >> 4) * 4;
  col0 = (wave & 1) * 64 + (lane & 15);
}

static __device__ __forceinline__ void epi_f32(const f32x4 acc[4][4],
                                               float* __restrict__ Ct, int ldc) {
  int row0, col0; frag_rc(row0, col0);
#pragma unroll
  for (int mi = 0; mi < 4; ++mi)
#pragma unroll
    for (int ni = 0; ni < 4; ++ni) {
      long base = (long)(row0 + mi * 16) * ldc + col0 + ni * 16;
#pragma unroll
      for (int t = 0; t < 4; ++t) Ct[base + (long)t * ldc] = acc[mi][ni][t];
    }
}

static __device__ __forceinline__ void epi_bf16(const f32x4 acc[4][4],
                                                uint16_t* __restrict__ Ct, int ldc) {
  int row0, col0; frag_rc(row0, col0);
#pragma unroll
  for (int mi = 0; mi < 4; ++mi)
#pragma unroll
    for (int ni = 0; ni < 4; ++ni) {
      long base = (long)(row0 + mi * 16) * ldc + col0 + ni * 16;
#pragma unroll
      for (int t = 0; t < 4; ++t) Ct[base + (long)t * ldc] = f2bf(acc[mi][ni][t]);
    }
}

static __device__ __forceinline__ void epi_split(const f32x4 acc[4][4],
                                                 uint16_t* __restrict__ Ch,
                                                 uint16_t* __restrict__ Cl, int ldc) {
  int row0, col0; frag_rc(row0, col0);
#pragma unroll
  for (int mi = 0; mi < 4; ++mi)
#pragma unroll
    for (int ni = 0; ni < 4; ++ni) {
      long base = (long)(row0 + mi * 16) * ldc + col0 + ni * 16;
#pragma unroll
      for (int t = 0; t < 4; ++t) {
        float v = acc[mi][ni][t];
        uint16_t hi = f2bf(v);
        Ch[base + (long)t * ldc] = hi;
        Cl[base + (long)t * ldc] = f2bf(v - bf2f(hi));
      }
    }
}

// ---------------------------------------------------------------------------
// Prep: transpose+cast weights. Wc1T/Wc2T: [T,H] bf16; WbT hi/lo: [H,H] bf16.
__global__ void prep_weights(const float* __restrict__ Wc1,
                             const float* __restrict__ Wc2,
                             const float* __restrict__ Wb,
                             uint16_t* __restrict__ Wc1T, uint16_t* __restrict__ Wc2T,
                             uint16_t* __restrict__ WbTh, uint16_t* __restrict__ WbTl) {
  int idx = blockIdx.x * 256 + threadIdx.x;
  if (idx < NT * NH) {
    int i = idx / NH, h = idx % NH;
    Wc1T[idx] = f2bf(Wc1[h * NT + i]);
    Wc2T[idx] = f2bf(Wc2[h * NT + i]);
  }
  if (idx < NH * NH) {
    int n = idx / NH, k = idx % NH;
    float w = Wb[k * NH + n];
    uint16_t hi = f2bf(w);
    WbTh[idx] = hi;
    WbTl[idx] = f2bf(w - bf2f(hi));
  }
}

// One block per (b,t) row: split q,p into bf16 hi/lo, pd = bf16(p*Wd[h]),
// and fold in the Wm GEMV (qWm/pWm row dots) via block reduction.
__global__ __launch_bounds__(256) void prep_qp(
    const float* __restrict__ q, const float* __restrict__ p,
    const float* __restrict__ Wd, const float* __restrict__ Wm,
    uint16_t* __restrict__ q_hi, uint16_t* __restrict__ q_lo,
    uint16_t* __restrict__ p_hi, uint16_t* __restrict__ p_lo,
    uint16_t* __restrict__ pd,
    float* __restrict__ qWm, float* __restrict__ pWm) {
  const int row = blockIdx.x;  // 0 .. NB*NT-1
  const long base = (long)row * NH;
  float sq = 0.f, sp = 0.f;
#pragma unroll
  for (int k = 0; k < 3; ++k) {
    int h = (int)threadIdx.x + 256 * k;
    long idx = base + h;
    float qv = q[idx], pv = p[idx];
    uint16_t qh = f2bf(qv);
    q_hi[idx] = qh; q_lo[idx] = f2bf(qv - bf2f(qh));
    uint16_t ph = f2bf(pv);
    p_hi[idx] = ph; p_lo[idx] = f2bf(pv - bf2f(ph));
    pd[idx] = f2bf(pv * Wd[h]);
    float w = Wm[h];
    sq += qv * w; sp += pv * w;
  }
  for (int o = 32; o; o >>= 1) { sq += __shfl_down(sq, o); sp += __shfl_down(sp, o); }
  __shared__ float red[8];
  int lane = threadIdx.x & 63, wv = threadIdx.x >> 6;
  if (lane == 0) { red[wv] = sq; red[4 + wv] = sp; }
  __syncthreads();
  if (threadIdx.x == 0) {
    qWm[row] = red[0] + red[1] + red[2] + red[3];
    pWm[row] = red[4] + red[5] + red[6] + red[7];
  }
}

// qT[b,h,t] = q_hi[b,t,h]  (LDS-tiled transpose, 32x32 tiles)
__global__ void transpose_q(const uint16_t* __restrict__ q_hi, uint16_t* __restrict__ qT) {
  __shared__ uint16_t tile[32][33];
  int b = blockIdx.z;
  int h0 = blockIdx.x * 32, t0 = blockIdx.y * 32;
  int tx = threadIdx.x & 31, ty = threadIdx.x >> 5;  // ty in [0,8)
  const uint16_t* src = q_hi + ((long)b * NT + t0) * NH + h0;
  for (int s = 0; s < 32; s += 8) tile[ty + s][tx] = src[(long)(ty + s) * NH + tx];
  __syncthreads();
  uint16_t* dst = qT + ((long)b * NH + h0) * NT + t0;
  for (int s = 0; s < 32; s += 8) dst[(long)(ty + s) * NT + tx] = tile[tx][ty + s];
}

// ---------------------------------------------------------------------------
// Fused whqT / whp / sd: grid (2, 6, 64); by -> (op, m-tile). 768 blocks.
//   op0: whqT[b,i,j] = sum_h Wc1[h,i] q[b,j,h]   A=Wc1T (shared), B=q_hi[b]
//   op1: whp [b,i,j] = sum_h p[b,i,h] Wc2[h,j]   A=p_hi[b],       B=Wc2T (shared)
//   op2: sd  [b,i,j] = sum_h pd[b,i,h] q[b,j,h]  A=pd[b],         B=q_hi[b]
__global__ __launch_bounds__(256) void gemm_fused3(
    const uint16_t* __restrict__ Wc1T, const uint16_t* __restrict__ Wc2T,
    const uint16_t* __restrict__ q_hi, const uint16_t* __restrict__ p_hi,
    const uint16_t* __restrict__ pd,
    uint16_t* __restrict__ whqT, uint16_t* __restrict__ whp, uint16_t* __restrict__ sd) {
  __shared__ __align__(16) uint16_t As[128 * BK];
  __shared__ __align__(16) uint16_t Bs[128 * BK];
  int bx, by, bz;
  xcd_chunk<2, 6, 64>(bx, by, bz);
  const int op = by >> 1;
  const long tm = (long)(by & 1) * 128, tn = (long)bx * 128;
  const long b = bz;
  const long sQP = (long)NT * NH, sTT = (long)NT * NT;
  const uint16_t* A; const uint16_t* B; uint16_t* C;
  if (op == 0)      { A = Wc1T + tm * NH;           B = q_hi + b * sQP + tn * NH; C = whqT + b * sTT; }
  else if (op == 1) { A = p_hi + b * sQP + tm * NH; B = Wc2T + tn * NH;           C = whp  + b * sTT; }
  else              { A = pd   + b * sQP + tm * NH; B = q_hi + b * sQP + tn * NH; C = sd   + b * sTT; }
  f32x4 acc[4][4];
  acc_zero(acc);
  gemm_product(A, B, NH, NH, NH, As, Bs, acc);
  epi_bf16(acc, C + tm * NT + tn, NT);
}

// pWb = p @ Wb, hi/lo split (3 products summed in f32 acc), epilogue re-splits.
__global__ __launch_bounds__(256) void gemm_pwb(
    const uint16_t* __restrict__ p_hi, const uint16_t* __restrict__ p_lo,
    const uint16_t* __restrict__ WbTh, const uint16_t* __restrict__ WbTl,
    uint16_t* __restrict__ pWbh, uint16_t* __restrict__ pWbl) {
  __shared__ __align__(16) uint16_t As[128 * BK];
  __shared__ __align__(16) uint16_t Bs[128 * BK];
  int bx, by, bz;
  xcd_chunk<6, 2, 64>(bx, by, bz);
  const long b = bz, tm = (long)by * 128, tn = (long)bx * 128;
  const long sQP = (long)NT * NH;
  const uint16_t* Ah = p_hi + b * sQP + tm * NH;
  const uint16_t* Al = p_lo + b * sQP + tm * NH;
  f32x4 acc[4][4];
  acc_zero(acc);
  gemm_product(Ah, WbTh + tn * NH, NH, NH, NH, As, Bs, acc);
  gemm_product(Ah, WbTl + tn * NH, NH, NH, NH, As, Bs, acc);
  gemm_product(Al, WbTh + tn * NH, NH, NH, NH, As, Bs, acc);
  epi_split(acc, pWbh + b * sQP + tm * NH + tn, pWbl + b * sQP + tm * NH + tn, NH);
}

// sb partial products, one product per block along z: grid (2, 2, 192).
//   pr0: pWbh @ q_hi^T -> sb0 ; pr1: pWbh @ q_lo^T -> sb1 ; pr2: pWbl @ q_hi^T -> sb2
// softmax_k sums the three f32 partials (order-of-f32-adds change only).
__global__ __launch_bounds__(256) void gemm_sb(
    const uint16_t* __restrict__ pWbh, const uint16_t* __restrict__ pWbl,
    const uint16_t* __restrict__ q_hi, const uint16_t* __restrict__ q_lo,
    float* __restrict__ sb0, float* __restrict__ sb1, float* __restrict__ sb2) {
  __shared__ __align__(16) uint16_t As[128 * BK];
  __shared__ __align__(16) uint16_t Bs[128 * BK];
  int bx, by, bz;
  xcd_chunk<2, 2, 192>(bx, by, bz);
  const int pr = bz >> 6;
  const long b = bz & 63, tm = (long)by * 128, tn = (long)bx * 128;
  const long sQP = (long)NT * NH, sTT = (long)NT * NT;
  const uint16_t* A = (pr == 2 ? pWbl : pWbh) + b * sQP + tm * NH;
  const uint16_t* B = (pr == 1 ? q_lo : q_hi) + b * sQP + tn * NH;
  float* C = (pr == 0 ? sb0 : (pr == 1 ? sb1 : sb2)) + b * sTT + tm * NT + tn;
  f32x4 acc[4][4];
  acc_zero(acc);
  gemm_product(A, B, NH, NH, NH, As, Bs, acc);
  epi_f32(acc, C, NT);
}

// Fused PV for all 4 attention outputs: grid (6, 8, 64); by -> (a, m-tile).
// out_a[b] = P_a[b] @ q[b]  with A = P_a [T,T], B = qT [H,T].
__global__ __launch_bounds__(256) void gemm_pv(
    const uint16_t* __restrict__ P, const uint16_t* __restrict__ qT,
    float* __restrict__ out) {
  __shared__ __align__(16) uint16_t As[128 * BK];
  __shared__ __align__(16) uint16_t Bs[128 * BK];
  int bx, by, bz;
  xcd_chunk<6, 8, 64>(bx, by, bz);
  const int a = by >> 1;
  const long tm = (long)(by & 1) * 128, tn = (long)bx * 128;
  const long b = bz;
  const long sQP = (long)NT * NH, sTT = (long)NT * NT;
  const long PB = (long)NB * sTT, nqp = (long)NB * sQP;
  const uint16_t* A = P + (long)a * PB + b * sTT + tm * NT;
  const uint16_t* B = qT + b * sQP + tn * NT;
  f32x4 acc[4][4];
  acc_zero(acc);
  gemm_product(A, B, NT, NT, NT, As, Bs, acc);
  epi_f32(acc, out + (long)a * nqp + b * sQP + tm * NH + tn, NH);
}

// ---------------------------------------------------------------------------
// One wave per (b,i) row: assemble 4 score rows, shuffle-reduce softmax, emit bf16 P.
// P layout: 4 contiguous [NB,NT,NT] blocks in order c,b,d,m.
__global__ __launch_bounds__(64) void softmax_k(
    const uint16_t* __restrict__ whp, const uint16_t* __restrict__ whqT,
    const float* __restrict__ sb0, const float* __restrict__ sb1,
    const float* __restrict__ sb2, const uint16_t* __restrict__ sd,
    const float* __restrict__ qWm, const float* __restrict__ pWm,
    const float* __restrict__ vc, const float* __restrict__ vd,
    const float* __restrict__ vm,
    uint16_t* __restrict__ P) {
  int bi = blockIdx.x;  // b*NT + i
  int b = bi >> 8, i = bi & 255;
  int lane = threadIdx.x;
  long rowoff = (long)bi * NT;
  const long PB = (long)NB * NT * NT;
  float vci = vc[i];
  float pwm = pWm[(long)b * NT + i];
  float vals[4][4];
#pragma unroll
  for (int u = 0; u < 4; ++u) {
    int j = lane + 64 * u;
    long off = rowoff + j;
    vals[0][u] = tanhf(bf2f(whp[off]) + bf2f(whqT[off])) * vci;   // vc per-i
    vals[1][u] = sb0[off] + sb1[off] + sb2[off];                   // bilinear hi/lo sum
    vals[2][u] = tanhf(bf2f(sd[off])) * vd[j];                     // vd per-j
    vals[3][u] = tanhf(qWm[(long)b * NT + j] - pwm) * vm[j];       // vm per-j
  }
#pragma unroll
  for (int a = 0; a < 4; ++a) {
    float m = fmaxf(fmaxf(vals[a][0], vals[a][1]), fmaxf(vals[a][2], vals[a][3]));
    for (int o = 32; o; o >>= 1) m = fmaxf(m, __shfl_xor(m, o));
    float e[4], s = 0.f;
#pragma unroll
    for (int u = 0; u < 4; ++u) { e[u] = __expf(vals[a][u] - m); s += e[u]; }
    for (int o = 32; o; o >>= 1) s += __shfl_xor(s, o);
    float inv = 1.f / s;
#pragma unroll
    for (int u = 0; u < 4; ++u)
      P[a * PB + rowoff + lane + 64 * u] = f2bf(e[u] * inv);
  }
}

// ---------------------------------------------------------------------------
extern "C" void kernel_launch(void* const* d_in, const int* in_sizes, int n_in,
                              void* d_out, int out_size, void* d_ws, size_t ws_size,
                              hipStream_t stream) {
  const float* q   = (const float*)d_in[0];
  const float* p   = (const float*)d_in[1];
  const float* Wc1 = (const float*)d_in[2];
  const float* Wc2 = (const float*)d_in[3];
  const float* vc  = (const float*)d_in[4];
  const float* Wb  = (const float*)d_in[5];
  const float* Wd  = (const float*)d_in[6];
  const float* vd  = (const float*)d_in[7];
  const float* Wm  = (const float*)d_in[8];
  const float* vm  = (const float*)d_in[9];
  (void)in_sizes; (void)n_in; (void)out_size; (void)ws_size;

  char* ws = (char*)d_ws;
  size_t o = 0;
  auto alloc = [&](size_t bytes) -> char* {
    char* r = ws + o;
    o = (o + bytes + 255) & ~(size_t)255;
    return r;
  };
  const size_t nqp = (size_t)NB * NT * NH;   // 12.58M
  const size_t ntt = (size_t)NB * NT * NT;   // 4.19M

  uint16_t* Wc1T = (uint16_t*)alloc((size_t)NT * NH * 2);
  uint16_t* Wc2T = (uint16_t*)alloc((size_t)NT * NH * 2);
  uint16_t* WbTh = (uint16_t*)alloc((size_t)NH * NH * 2);
  uint16_t* WbTl = (uint16_t*)alloc((size_t)NH * NH * 2);
  uint16_t* q_hi = (uint16_t*)alloc(nqp * 2);
  uint16_t* q_lo = (uint16_t*)alloc(nqp * 2);
  uint16_t* p_hi = (uint16_t*)alloc(nqp * 2);
  uint16_t* p_lo = (uint16_t*)alloc(nqp * 2);   // dead after gemm_pwb -> reused as sb1
  uint16_t* pd   = (uint16_t*)alloc(nqp * 2);   // dead after gemm_fused3 -> reused as sb2
  uint16_t* qT   = (uint16_t*)alloc(nqp * 2);
  float*    qWmB = (float*)alloc((size_t)NB * NT * 4);
  float*    pWmB = (float*)alloc((size_t)NB * NT * 4);
  uint16_t* whp  = (uint16_t*)alloc(ntt * 2);
  uint16_t* whqT = (uint16_t*)alloc(ntt * 2);
  uint16_t* pWbh = (uint16_t*)alloc(nqp * 2);
  uint16_t* pWbl = (uint16_t*)alloc(nqp * 2);
  float*    sb0  = (float*)alloc(ntt * 4);
  uint16_t* sd   = (uint16_t*)alloc(ntt * 2);
  uint16_t* P    = (uint16_t*)alloc(4 * ntt * 2);

  // Alias the sb hi/lo partials into buffers that are dead by the time gemm_sb
  // runs (p_lo: last read by gemm_pwb; pd: last read by gemm_fused3).
  // ntt*4 bytes (16.8 MB) fits in nqp*2 bytes (25.2 MB).
  float* sb1 = (float*)p_lo;
  float* sb2 = (float*)pd;

  prep_weights<<<dim3((NH * NH + 255) / 256), dim3(256), 0, stream>>>(
      Wc1, Wc2, Wb, Wc1T, Wc2T, WbTh, WbTl);
  prep_qp<<<dim3(NB * NT), dim3(256), 0, stream>>>(
      q, p, Wd, Wm, q_hi, q_lo, p_hi, p_lo, pd, qWmB, pWmB);
  transpose_q<<<dim3(NH / 32, NT / 32, NB), dim3(256), 0, stream>>>(q_hi, qT);

  gemm_fused3<<<dim3(2, 6, NB), dim3(256), 0, stream>>>(
      Wc1T, Wc2T, q_hi, p_hi, pd, whqT, whp, sd);

  gemm_pwb<<<dim3(NH / 128, 2, NB), dim3(256), 0, stream>>>(
      p_hi, p_lo, WbTh, WbTl, pWbh, pWbl);

  gemm_sb<<<dim3(2, 2, 3 * NB), dim3(256), 0, stream>>>(
      pWbh, pWbl, q_hi, q_lo, sb0, sb1, sb2);

  softmax_k<<<dim3(NB * NT), dim3(64), 0, stream>>>(
      whp, whqT, sb0, sb1, sb2, sd, qWmB, pWmB, vc, vd, vm, P);

  gemm_pv<<<dim3(NH / 128, 8, NB), dim3(256), 0, stream>>>(P, qT, (float*)d_out);
}

// Round 2
// 555.179 us; speedup vs baseline: 1.2617x; 1.0391x over previous
//
#include <hip/hip_runtime.h>
#include <hip/hip_bf16.h>
#include <stdint.h>

#define NB 64
#define NT 256
#define NH 768

typedef float f32x4 __attribute__((ext_vector_type(4)));
typedef __bf16 bf16x8 __attribute__((ext_vector_type(8)));

static __device__ __forceinline__ uint16_t f2bf(float f) {
  union { float f; uint32_t u; } v; v.f = f;
  uint32_t r = v.u + 0x7FFFu + ((v.u >> 16) & 1u);
  return (uint16_t)(r >> 16);
}
static __device__ __forceinline__ float bf2f(uint16_t h) {
  union { uint32_t u; float f; } v; v.u = ((uint32_t)h) << 16;
  return v.f;
}

// global -> LDS direct DMA, 16B per lane. LDS dest = wave-uniform base + lane*16.
typedef const __attribute__((address_space(1))) uint32_t* gp1_t;
typedef __attribute__((address_space(3))) uint32_t* lp3_t;
static __device__ __forceinline__ void gload_lds16(const uint16_t* g, uint16_t* l) {
  __builtin_amdgcn_global_load_lds((gp1_t)g, (lp3_t)l, 16, 0, 0);
}

// Chunked bijective XCD swizzle over a flat grid (nwg % 8 == 0).
static __device__ __forceinline__ int xcd_flat(int nwg) {
  int lin = (int)blockIdx.x;
  return (lin & 7) * (nwg >> 3) + (lin >> 3);
}

// ---------------------------------------------------------------------------
// 256x256 pipelined GEMM core (T3+T4+T2+T5): C += A(256,K) * B(256,K)^T.
// 8 waves (2m x 4n), per-wave 128x64 output = acc[8][4] f32x4.
// BK=32, 3 rolling LDS slots of 32 KB (A 16K + B 16K), stage tile kt+2 while
// computing kt; counted vmcnt(5) once per K-tile (loads stay in flight across
// barriers); 2 barriers per K-tile; LDS XOR-swizzle k^=((row>>3)&1)<<4 elems,
// applied as pre-swizzled global source (linear gload_lds dest) + swizzled read.
#define SLOT_U16 16384

static __device__ __forceinline__ void stage_part(
    const uint16_t* __restrict__ Ap, const uint16_t* __restrict__ Bp,
    int k0, int lda, int ldb, int part, uint16_t* __restrict__ slot,
    int wid, int lane) {
  const int isB = part >> 1;
  const int row = (part & 1) * 128 + wid * 16 + (lane >> 2);      // row bit3 = lane bit5
  const int kcol = ((lane & 3) * 8) ^ (((lane >> 5) & 1) << 4);   // inverse swizzle at source
  const uint16_t* src = isB ? Bp + (long)row * ldb + (k0 + kcol)
                            : Ap + (long)row * lda + (k0 + kcol);
  gload_lds16(src, slot + part * 4096 + wid * 512);
}

template <int NPROD, int NKPER>
static __device__ __forceinline__ void gemm256_core(
    const uint16_t* __restrict__ A0, const uint16_t* __restrict__ A1,
    const uint16_t* __restrict__ A2,
    const uint16_t* __restrict__ B0, const uint16_t* __restrict__ B1,
    const uint16_t* __restrict__ B2,
    int lda, int ldb, uint16_t* __restrict__ lds, f32x4 acc[8][4]) {
  const int tid = (int)threadIdx.x;
  const int wid = tid >> 6, lane = tid & 63;
  const int r = lane & 15, quad = lane >> 4;
  const int wm = wid >> 2, wn = wid & 3;
  const int ks = (quad * 8) ^ ((r >> 3) << 4);          // swizzled k-slot (u16 units)
  const int abase = (wm * 128 + r) * 32 + ks;
  const int bbase = 8192 + (wn * 64 + r) * 32 + ks;
  constexpr int nk = NPROD * NKPER;

#define TILE_AB(t, Ap, Bp, k0)                                      \
  {                                                                 \
    int pr_ = 0, kk_ = (t);                                         \
    if (NPROD > 1) { pr_ = (t) / NKPER; kk_ = (t) - pr_ * NKPER; }  \
    Ap = pr_ == 0 ? A0 : (pr_ == 1 ? A1 : A2);                      \
    Bp = pr_ == 0 ? B0 : (pr_ == 1 ? B1 : B2);                      \
    k0 = kk_ * 32;                                                  \
  }

  // Prologue: fully stage tiles 0 (slot0) and 1 (slot1): 8 loads/wave in flight.
  {
    const uint16_t* Ap; const uint16_t* Bp; int k0;
    TILE_AB(0, Ap, Bp, k0);
#pragma unroll
    for (int s = 0; s < 4; ++s) stage_part(Ap, Bp, k0, lda, ldb, s, lds, wid, lane);
    TILE_AB(1, Ap, Bp, k0);
#pragma unroll
    for (int s = 0; s < 4; ++s) stage_part(Ap, Bp, k0, lda, ldb, s, lds + SLOT_U16, wid, lane);
  }

  int slot = 0;
  for (int kt = 0; kt < nk; ++kt) {
    uint16_t* cur = lds + slot * SLOT_U16;
    int ns = slot + 2; if (ns >= 3) ns -= 3;
    uint16_t* nxt = lds + ns * SLOT_U16;   // slot read in iter kt-1: free (its end barrier passed)
    const uint16_t* An = A0; const uint16_t* Bn = B0; int k0n = 0;
    const bool more2 = (kt + 2 < nk), more1 = (kt + 1 < nk);
    if (more2) TILE_AB(kt + 2, An, Bn, k0n);

#pragma unroll
    for (int p = 0; p < 4; ++p) {
      if (more2) stage_part(An, Bn, k0n, lda, ldb, p, nxt, wid, lane);
      if (p == 0) {
        // Outstanding after this phase's stage: kt+1's 4 + 1 just issued.
        // Waiting to 5 retires exactly tile kt's 4 loads (vmcnt retires in order).
        if (more2)      asm volatile("s_waitcnt vmcnt(5)" ::: "memory");
        else if (more1) asm volatile("s_waitcnt vmcnt(4)" ::: "memory");
        else            asm volatile("s_waitcnt vmcnt(0)" ::: "memory");
        __builtin_amdgcn_s_barrier();     // all waves' tile-kt loads landed
      }
      const int mg = p >> 1, ng = p & 1;  // quadrant: 4 mi x 2 ni x 8 MFMA
      bf16x8 av[4]; bf16x8 bv[2];
#pragma unroll
      for (int i = 0; i < 4; ++i)
        av[i] = *(const bf16x8*)&cur[abase + (mg * 4 + i) * 512];
#pragma unroll
      for (int j = 0; j < 2; ++j)
        bv[j] = *(const bf16x8*)&cur[bbase + (ng * 2 + j) * 512];
      if (p == 3) {
        // All reads of `cur` retired before any wave stages over it next iter.
        asm volatile("s_waitcnt lgkmcnt(0)" ::: "memory");
        __builtin_amdgcn_s_barrier();
      }
      __builtin_amdgcn_s_setprio(1);
#pragma unroll
      for (int i = 0; i < 4; ++i)
#pragma unroll
        for (int j = 0; j < 2; ++j)
          acc[mg * 4 + i][ng * 2 + j] = __builtin_amdgcn_mfma_f32_16x16x32_bf16(
              av[i], bv[j], acc[mg * 4 + i][ng * 2 + j], 0, 0, 0);
      __builtin_amdgcn_s_setprio(0);
    }
    ++slot; if (slot == 3) slot = 0;
  }
#undef TILE_AB
}

static __device__ __forceinline__ void acc_zero8(f32x4 acc[8][4]) {
#pragma unroll
  for (int i = 0; i < 8; ++i)
#pragma unroll
    for (int j = 0; j < 4; ++j) acc[i][j] = (f32x4){0.f, 0.f, 0.f, 0.f};
}

// C/D frag: col = lane&15, row = quad*4 + t   [verified m89/m91]
static __device__ __forceinline__ void epi256_f32(const f32x4 acc[8][4],
                                                  float* __restrict__ C, int ldc) {
  const int lane = (int)threadIdx.x & 63, wid = (int)threadIdx.x >> 6;
  const int r = lane & 15, quad = lane >> 4;
  const int wm = wid >> 2, wn = wid & 3;
#pragma unroll
  for (int mi = 0; mi < 8; ++mi) {
    long row = wm * 128 + mi * 16 + quad * 4;
#pragma unroll
    for (int ni = 0; ni < 4; ++ni) {
      long col = wn * 64 + ni * 16 + r;
#pragma unroll
      for (int t = 0; t < 4; ++t) C[(row + t) * ldc + col] = acc[mi][ni][t];
    }
  }
}

static __device__ __forceinline__ void epi256_bf16(const f32x4 acc[8][4],
                                                   uint16_t* __restrict__ C, int ldc) {
  const int lane = (int)threadIdx.x & 63, wid = (int)threadIdx.x >> 6;
  const int r = lane & 15, quad = lane >> 4;
  const int wm = wid >> 2, wn = wid & 3;
#pragma unroll
  for (int mi = 0; mi < 8; ++mi) {
    long row = wm * 128 + mi * 16 + quad * 4;
#pragma unroll
    for (int ni = 0; ni < 4; ++ni) {
      long col = wn * 64 + ni * 16 + r;
#pragma unroll
      for (int t = 0; t < 4; ++t) C[(row + t) * ldc + col] = f2bf(acc[mi][ni][t]);
    }
  }
}

static __device__ __forceinline__ void epi256_split(const f32x4 acc[8][4],
                                                    uint16_t* __restrict__ Ch,
                                                    uint16_t* __restrict__ Cl, int ldc) {
  const int lane = (int)threadIdx.x & 63, wid = (int)threadIdx.x >> 6;
  const int r = lane & 15, quad = lane >> 4;
  const int wm = wid >> 2, wn = wid & 3;
#pragma unroll
  for (int mi = 0; mi < 8; ++mi) {
    long row = wm * 128 + mi * 16 + quad * 4;
#pragma unroll
    for (int ni = 0; ni < 4; ++ni) {
      long col = wn * 64 + ni * 16 + r;
#pragma unroll
      for (int t = 0; t < 4; ++t) {
        float v = acc[mi][ni][t];
        uint16_t hi = f2bf(v);
        Ch[(row + t) * ldc + col] = hi;
        Cl[(row + t) * ldc + col] = f2bf(v - bf2f(hi));
      }
    }
  }
}

// ---------------------------------------------------------------------------
// Merged prep: [0,16384) per-row qp split + Wm GEMV; [16384,28672) q transpose
// (from f32 q directly); [28672,30976) weight transpose/cast.
__global__ __launch_bounds__(256) void prep_all(
    const float* __restrict__ q, const float* __restrict__ p,
    const float* __restrict__ Wc1, const float* __restrict__ Wc2,
    const float* __restrict__ Wb, const float* __restrict__ Wd,
    const float* __restrict__ Wm,
    uint16_t* __restrict__ q_hi, uint16_t* __restrict__ q_lo,
    uint16_t* __restrict__ p_hi, uint16_t* __restrict__ p_lo,
    uint16_t* __restrict__ pd, uint16_t* __restrict__ qT,
    uint16_t* __restrict__ Wc1T, uint16_t* __restrict__ Wc2T,
    uint16_t* __restrict__ WbTh, uint16_t* __restrict__ WbTl,
    float* __restrict__ qWm, float* __restrict__ pWm) {
  __shared__ float smem[32 * 33];
  const int blk = (int)blockIdx.x;
  const int tid = (int)threadIdx.x;
  if (blk < NB * NT) {
    const long base = (long)blk * NH;
    float sq = 0.f, sp = 0.f;
#pragma unroll
    for (int k = 0; k < 3; ++k) {
      int h = tid + 256 * k;
      long idx = base + h;
      float qv = q[idx], pv = p[idx];
      uint16_t qh = f2bf(qv);
      q_hi[idx] = qh; q_lo[idx] = f2bf(qv - bf2f(qh));
      uint16_t ph = f2bf(pv);
      p_hi[idx] = ph; p_lo[idx] = f2bf(pv - bf2f(ph));
      pd[idx] = f2bf(pv * Wd[h]);
      float w = Wm[h];
      sq += qv * w; sp += pv * w;
    }
    for (int o = 32; o; o >>= 1) { sq += __shfl_down(sq, o); sp += __shfl_down(sp, o); }
    int lane = tid & 63, wv = tid >> 6;
    if (lane == 0) { smem[wv] = sq; smem[4 + wv] = sp; }
    __syncthreads();
    if (tid == 0) {
      qWm[blk] = smem[0] + smem[1] + smem[2] + smem[3];
      pWm[blk] = smem[4] + smem[5] + smem[6] + smem[7];
    }
  } else if (blk < NB * NT + 24 * 8 * NB) {
    // qT[b,h,t] = bf16(q[b,t,h]), 32x32 LDS tiles
    int t = blk - NB * NT;
    int ht = t % 24, tt = (t / 24) % 8, b = t / 192;
    int h0 = ht * 32, t0 = tt * 32;
    int tx = tid & 31, ty = tid >> 5;  // ty in [0,8)
    const float* src = q + ((long)b * NT + t0) * NH + h0;
    for (int s = 0; s < 32; s += 8) smem[(ty + s) * 33 + tx] = src[(long)(ty + s) * NH + tx];
    __syncthreads();
    uint16_t* dst = qT + ((long)b * NH + h0) * NT + t0;
    for (int s = 0; s < 32; s += 8) dst[(long)(ty + s) * NT + tx] = f2bf(smem[tx * 33 + ty + s]);
  } else {
    int idx = (blk - (NB * NT + 24 * 8 * NB)) * 256 + tid;
    if (idx < NT * NH) {
      int i = idx / NH, h = idx % NH;
      Wc1T[idx] = f2bf(Wc1[h * NT + i]);
      Wc2T[idx] = f2bf(Wc2[h * NT + i]);
    }
    if (idx < NH * NH) {
      int n = idx / NH, k = idx % NH;
      float w = Wb[k * NH + n];
      uint16_t hi = f2bf(w);
      WbTh[idx] = hi;
      WbTl[idx] = f2bf(w - bf2f(hi));
    }
  }
}

// ---------------------------------------------------------------------------
// Launch A (384 blocks): first 192 = fused3 (w = b*3+op), rest = pwb (w2 = b*3+nt).
//   op0: whqT[b] = Wc1T x q_hi[b]^T ; op1: whp[b] = p_hi[b] x Wc2T^T
//   op2: sd[b]   = pd[b] x q_hi[b]^T
//   pwb: pWb[b] cols [nt*256,+256) = p x Wb, hi/lo 3-product, split epilogue.
__global__ __launch_bounds__(512, 2) void gemm_big3(
    const uint16_t* __restrict__ Wc1T, const uint16_t* __restrict__ Wc2T,
    const uint16_t* __restrict__ q_hi, const uint16_t* __restrict__ p_hi,
    const uint16_t* __restrict__ p_lo, const uint16_t* __restrict__ pd,
    const uint16_t* __restrict__ WbTh, const uint16_t* __restrict__ WbTl,
    uint16_t* __restrict__ whqT, uint16_t* __restrict__ whp,
    uint16_t* __restrict__ sd,
    uint16_t* __restrict__ pWbh, uint16_t* __restrict__ pWbl) {
  __shared__ __align__(16) uint16_t lds[3 * SLOT_U16];
  const long sQP = (long)NT * NH, sTT = (long)NT * NT;
  int w = xcd_flat(384);
  f32x4 acc[8][4];
  acc_zero8(acc);
  if (w < 192) {
    const int b = w / 3, op = w - b * 3;
    const uint16_t* A; const uint16_t* B; uint16_t* C;
    if (op == 0)      { A = Wc1T;           B = q_hi + b * sQP; C = whqT + b * sTT; }
    else if (op == 1) { A = p_hi + b * sQP; B = Wc2T;           C = whp  + b * sTT; }
    else              { A = pd   + b * sQP; B = q_hi + b * sQP; C = sd   + b * sTT; }
    gemm256_core<1, 24>(A, nullptr, nullptr, B, nullptr, nullptr, NH, NH, lds, acc);
    epi256_bf16(acc, C, NT);
  } else {
    const int w2 = w - 192;
    const int b = w2 / 3, nt = w2 - b * 3;
    const uint16_t* Ah = p_hi + b * sQP;
    const uint16_t* Al = p_lo + b * sQP;
    const uint16_t* Bh = WbTh + (long)nt * 256 * NH;
    const uint16_t* Bl = WbTl + (long)nt * 256 * NH;
    gemm256_core<3, 24>(Ah, Ah, Al, Bh, Bl, Bh, NH, NH, lds, acc);
    epi256_split(acc, pWbh + b * sQP + nt * 256, pWbl + b * sQP + nt * 256, NH);
  }
}

// sb partials (192 blocks, w = b*3+pr):
//   pr0: pWbh x q_hi^T -> sb0 ; pr1: pWbh x q_lo^T -> sb1 ; pr2: pWbl x q_hi^T -> sb2
__global__ __launch_bounds__(512, 2) void gemm_sb(
    const uint16_t* __restrict__ pWbh, const uint16_t* __restrict__ pWbl,
    const uint16_t* __restrict__ q_hi, const uint16_t* __restrict__ q_lo,
    float* __restrict__ sb0, float* __restrict__ sb1, float* __restrict__ sb2) {
  __shared__ __align__(16) uint16_t lds[3 * SLOT_U16];
  const long sQP = (long)NT * NH, sTT = (long)NT * NT;
  int w = xcd_flat(192);
  const int b = w / 3, pr = w - b * 3;
  const uint16_t* A = (pr == 2 ? pWbl : pWbh) + b * sQP;
  const uint16_t* B = (pr == 1 ? q_lo : q_hi) + b * sQP;
  float* C = (pr == 0 ? sb0 : (pr == 1 ? sb1 : sb2)) + b * sTT;
  f32x4 acc[8][4];
  acc_zero8(acc);
  gemm256_core<1, 24>(A, nullptr, nullptr, B, nullptr, nullptr, NH, NH, lds, acc);
  epi256_f32(acc, C, NT);
}

// PV (768 blocks, w = b*12 + a*3 + nt): out_a[b] cols [nt*256,+256) = P_a[b] x q[b]
__global__ __launch_bounds__(512, 2) void gemm_pv(
    const uint16_t* __restrict__ P, const uint16_t* __restrict__ qT,
    float* __restrict__ out) {
  __shared__ __align__(16) uint16_t lds[3 * SLOT_U16];
  const long sQP = (long)NT * NH, sTT = (long)NT * NT;
  const long PB = (long)NB * sTT, nqp = (long)NB * sQP;
  int w = xcd_flat(768);
  const int b = w / 12, rem = w - b * 12;
  const int a = rem >> 2 == 0 ? 0 : rem / 3, nt = rem - (rem / 3) * 3;
  const uint16_t* A = P + (long)(rem / 3) * PB + b * sTT;
  const uint16_t* B = qT + b * sQP + (long)nt * 256 * NT;
  f32x4 acc[8][4];
  acc_zero8(acc);
  gemm256_core<1, 8>(A, nullptr, nullptr, B, nullptr, nullptr, NT, NT, lds, acc);
  (void)a;
  epi256_f32(acc, out + (long)(rem / 3) * nqp + b * sQP + (long)nt * 256, NH);
}

// ---------------------------------------------------------------------------
// One wave per (b,i) row: assemble 4 score rows, shuffle-reduce softmax, emit bf16 P.
__global__ __launch_bounds__(64) void softmax_k(
    const uint16_t* __restrict__ whp, const uint16_t* __restrict__ whqT,
    const float* __restrict__ sb0, const float* __restrict__ sb1,
    const float* __restrict__ sb2, const uint16_t* __restrict__ sd,
    const float* __restrict__ qWm, const float* __restrict__ pWm,
    const float* __restrict__ vc, const float* __restrict__ vd,
    const float* __restrict__ vm,
    uint16_t* __restrict__ P) {
  int bi = blockIdx.x;  // b*NT + i
  int b = bi >> 8, i = bi & 255;
  int lane = threadIdx.x;
  long rowoff = (long)bi * NT;
  const long PB = (long)NB * NT * NT;
  float vci = vc[i];
  float pwm = pWm[(long)b * NT + i];
  float vals[4][4];
#pragma unroll
  for (int u = 0; u < 4; ++u) {
    int j = lane + 64 * u;
    long off = rowoff + j;
    vals[0][u] = tanhf(bf2f(whp[off]) + bf2f(whqT[off])) * vci;   // vc per-i
    vals[1][u] = sb0[off] + sb1[off] + sb2[off];                   // bilinear hi/lo sum
    vals[2][u] = tanhf(bf2f(sd[off])) * vd[j];                     // vd per-j
    vals[3][u] = tanhf(qWm[(long)b * NT + j] - pwm) * vm[j];       // vm per-j
  }
#pragma unroll
  for (int a = 0; a < 4; ++a) {
    float m = fmaxf(fmaxf(vals[a][0], vals[a][1]), fmaxf(vals[a][2], vals[a][3]));
    for (int o = 32; o; o >>= 1) m = fmaxf(m, __shfl_xor(m, o));
    float e[4], s = 0.f;
#pragma unroll
    for (int u = 0; u < 4; ++u) { e[u] = __expf(vals[a][u] - m); s += e[u]; }
    for (int o = 32; o; o >>= 1) s += __shfl_xor(s, o);
    float inv = 1.f / s;
#pragma unroll
    for (int u = 0; u < 4; ++u)
      P[a * PB + rowoff + lane + 64 * u] = f2bf(e[u] * inv);
  }
}

// ---------------------------------------------------------------------------
extern "C" void kernel_launch(void* const* d_in, const int* in_sizes, int n_in,
                              void* d_out, int out_size, void* d_ws, size_t ws_size,
                              hipStream_t stream) {
  const float* q   = (const float*)d_in[0];
  const float* p   = (const float*)d_in[1];
  const float* Wc1 = (const float*)d_in[2];
  const float* Wc2 = (const float*)d_in[3];
  const float* vc  = (const float*)d_in[4];
  const float* Wb  = (const float*)d_in[5];
  const float* Wd  = (const float*)d_in[6];
  const float* vd  = (const float*)d_in[7];
  const float* Wm  = (const float*)d_in[8];
  const float* vm  = (const float*)d_in[9];
  (void)in_sizes; (void)n_in; (void)out_size; (void)ws_size;

  char* ws = (char*)d_ws;
  size_t o = 0;
  auto alloc = [&](size_t bytes) -> char* {
    char* r = ws + o;
    o = (o + bytes + 255) & ~(size_t)255;
    return r;
  };
  const size_t nqp = (size_t)NB * NT * NH;   // 12.58M
  const size_t ntt = (size_t)NB * NT * NT;   // 4.19M

  uint16_t* Wc1T = (uint16_t*)alloc((size_t)NT * NH * 2);
  uint16_t* Wc2T = (uint16_t*)alloc((size_t)NT * NH * 2);
  uint16_t* WbTh = (uint16_t*)alloc((size_t)NH * NH * 2);
  uint16_t* WbTl = (uint16_t*)alloc((size_t)NH * NH * 2);
  uint16_t* q_hi = (uint16_t*)alloc(nqp * 2);
  uint16_t* q_lo = (uint16_t*)alloc(nqp * 2);
  uint16_t* p_hi = (uint16_t*)alloc(nqp * 2);
  uint16_t* p_lo = (uint16_t*)alloc(nqp * 2);   // dead after gemm_big3 -> reused as sb1
  uint16_t* pd   = (uint16_t*)alloc(nqp * 2);   // dead after gemm_big3 -> reused as sb2
  uint16_t* qT   = (uint16_t*)alloc(nqp * 2);
  float*    qWmB = (float*)alloc((size_t)NB * NT * 4);
  float*    pWmB = (float*)alloc((size_t)NB * NT * 4);
  uint16_t* whp  = (uint16_t*)alloc(ntt * 2);
  uint16_t* whqT = (uint16_t*)alloc(ntt * 2);
  uint16_t* pWbh = (uint16_t*)alloc(nqp * 2);
  uint16_t* pWbl = (uint16_t*)alloc(nqp * 2);
  float*    sb0  = (float*)alloc(ntt * 4);
  uint16_t* sd   = (uint16_t*)alloc(ntt * 2);
  uint16_t* P    = (uint16_t*)alloc(4 * ntt * 2);

  // sb partials alias buffers dead by the time gemm_sb runs.
  float* sb1 = (float*)p_lo;
  float* sb2 = (float*)pd;

  prep_all<<<dim3(NB * NT + 24 * 8 * NB + (NH * NH + 255) / 256), dim3(256), 0, stream>>>(
      q, p, Wc1, Wc2, Wb, Wd, Wm,
      q_hi, q_lo, p_hi, p_lo, pd, qT, Wc1T, Wc2T, WbTh, WbTl, qWmB, pWmB);

  gemm_big3<<<dim3(384), dim3(512), 0, stream>>>(
      Wc1T, Wc2T, q_hi, p_hi, p_lo, pd, WbTh, WbTl,
      whqT, whp, sd, pWbh, pWbl);

  gemm_sb<<<dim3(192), dim3(512), 0, stream>>>(
      pWbh, pWbl, q_hi, q_lo, sb0, sb1, sb2);

  softmax_k<<<dim3(NB * NT), dim3(64), 0, stream>>>(
      whp, whqT, sb0, sb1, sb2, sd, qWmB, pWmB, vc, vd, vm, P);

  gemm_pv<<<dim3(768), dim3(512), 0, stream>>>(P, qT, (float*)d_out);
}

// Round 3
// 543.625 us; speedup vs baseline: 1.2885x; 1.0213x over previous
//
#include <hip/hip_runtime.h>
#include <hip/hip_bf16.h>
#include <stdint.h>

#define NB 64
#define NT 256
#define NH 768

typedef float f32x4 __attribute__((ext_vector_type(4)));
typedef __bf16 bf16x8 __attribute__((ext_vector_type(8)));

static __device__ __forceinline__ uint16_t f2bf(float f) {
  union { float f; uint32_t u; } v; v.f = f;
  uint32_t r = v.u + 0x7FFFu + ((v.u >> 16) & 1u);
  return (uint16_t)(r >> 16);
}
static __device__ __forceinline__ float bf2f(uint16_t h) {
  union { uint32_t u; float f; } v; v.u = ((uint32_t)h) << 16;
  return v.f;
}

// global -> LDS direct DMA, 16B per lane. LDS dest = wave-uniform base + lane*16.
typedef const __attribute__((address_space(1))) uint32_t* gp1_t;
typedef __attribute__((address_space(3))) uint32_t* lp3_t;
static __device__ __forceinline__ void gload_lds16(const uint16_t* g, uint16_t* l) {
  __builtin_amdgcn_global_load_lds((gp1_t)g, (lp3_t)l, 16, 0, 0);
}

// ---------------------------------------------------------------------------
// 256x128 pipelined GEMM core: C += A(256,K) * B(128,K)^T.
// 4 waves (2m x 2n), per-wave 128x64 output = acc[8][4] f32x4 (AGPRs).
// BK=32, 3 rolling LDS slots of 24 KB (A 16K + B 8K), stage tile kt+2 while
// computing kt; counted vmcnt(9/6/0); 2 barriers per K-tile; fragments read
// ONCE per K-tile (av[8] + bv[4] = 12 b128/wave -> LDS 1152 cyc < MFMA 1242
// cyc per CU at 2 blocks/CU). LDS XOR-swizzle k^=((row>>3)&1)<<4 elems applied
// as pre-swizzled global source (linear gload_lds dest) + swizzled read.
#define SLOT_U16 12288

// Stage parts [P0,P1) of one K-tile. Part 0..3 = A rows part*64..; 4..5 = B rows.
template <int P0, int P1>
static __device__ __forceinline__ void stageN(
    const uint16_t* __restrict__ Ap, const uint16_t* __restrict__ Bp,
    int k0, int lda, int ldb, uint16_t* __restrict__ slot, int wid, int lane) {
#pragma unroll
  for (int part = P0; part < P1; ++part) {
    const bool isB = part >= 4;
    const int row = (isB ? (part - 4) : part) * 64 + wid * 16 + (lane >> 2);
    const int kcol = ((lane & 3) * 8) ^ (((lane >> 5) & 1) << 4);  // inverse swizzle at source
    const uint16_t* src = (isB ? Bp + (long)row * ldb : Ap + (long)row * lda) + k0 + kcol;
    gload_lds16(src, slot + part * 2048 + wid * 512);
  }
}

template <int NPROD, int NKPER>
static __device__ __forceinline__ void gemm_core(
    const uint16_t* __restrict__ A0, const uint16_t* __restrict__ A1,
    const uint16_t* __restrict__ A2,
    const uint16_t* __restrict__ B0, const uint16_t* __restrict__ B1,
    const uint16_t* __restrict__ B2,
    int lda, int ldb, uint16_t* __restrict__ lds, f32x4 acc[8][4]) {
  const int tid = (int)threadIdx.x;
  const int wid = tid >> 6, lane = tid & 63;
  const int r = lane & 15, quad = lane >> 4;
  const int wm = wid >> 1, wn = wid & 1;
  const int ks = (quad * 8) ^ ((r >> 3) << 4);          // swizzled k-slot (u16 units)
  const int abase = (wm * 128 + r) * 32 + ks;           // + frag*512
  const int bbase = 8192 + (wn * 64 + r) * 32 + ks;     // + frag*512
  constexpr int nk = NPROD * NKPER;

#define TILE_AB(t, Ap, Bp, k0)                                      \
  {                                                                 \
    int pr_ = 0, kk_ = (t);                                         \
    if (NPROD > 1) { pr_ = (t) / NKPER; kk_ = (t) - pr_ * NKPER; }  \
    Ap = pr_ == 0 ? A0 : (pr_ == 1 ? A1 : A2);                      \
    Bp = pr_ == 0 ? B0 : (pr_ == 1 ? B1 : B2);                      \
    k0 = kk_ * 32;                                                  \
  }

  // Prologue: fully stage tiles 0 (slot0) and 1 (slot1): 12 loads/wave in flight.
  {
    const uint16_t* Ap; const uint16_t* Bp; int k0;
    TILE_AB(0, Ap, Bp, k0);
    stageN<0, 6>(Ap, Bp, k0, lda, ldb, lds, wid, lane);
    TILE_AB(1, Ap, Bp, k0);
    stageN<0, 6>(Ap, Bp, k0, lda, ldb, lds + SLOT_U16, wid, lane);
  }

  int slot = 0;
  for (int kt = 0; kt < nk; ++kt) {
    uint16_t* cur = lds + slot * SLOT_U16;
    int ns = slot + 2; if (ns >= 3) ns -= 3;
    uint16_t* nxt = lds + ns * SLOT_U16;  // read finished at iter kt-1's end barrier
    const uint16_t* An = A0; const uint16_t* Bn = B0; int k0n = 0;
    const bool more2 = (kt + 2 < nk), more1 = (kt + 1 < nk);
    if (more2) TILE_AB(kt + 2, An, Bn, k0n);

    // ---- phase 0: stage A-half of kt+2, sync tile kt, compute m-rows 0..63
    if (more2) stageN<0, 3>(An, Bn, k0n, lda, ldb, nxt, wid, lane);
    // Outstanding: kt's 6 + kt+1's 6 + 3 just issued = 15; wait to 9 retires
    // exactly tile kt's 6 (vmcnt retires in order).
    if (more2)      asm volatile("s_waitcnt vmcnt(9)" ::: "memory");
    else if (more1) asm volatile("s_waitcnt vmcnt(6)" ::: "memory");
    else            asm volatile("s_waitcnt vmcnt(0)" ::: "memory");
    __builtin_amdgcn_s_barrier();  // all waves' tile-kt loads landed

    bf16x8 av[4], bv[4];
#pragma unroll
    for (int i = 0; i < 4; ++i) av[i] = *(const bf16x8*)&cur[abase + i * 512];
#pragma unroll
    for (int j = 0; j < 4; ++j) bv[j] = *(const bf16x8*)&cur[bbase + j * 512];
    __builtin_amdgcn_s_setprio(1);
#pragma unroll
    for (int i = 0; i < 4; ++i)
#pragma unroll
      for (int j = 0; j < 4; ++j)
        acc[i][j] = __builtin_amdgcn_mfma_f32_16x16x32_bf16(av[i], bv[j], acc[i][j], 0, 0, 0);
    __builtin_amdgcn_s_setprio(0);

    // ---- phase 1: stage B-half of kt+2, compute m-rows 64..127 (bv reused)
    if (more2) stageN<3, 6>(An, Bn, k0n, lda, ldb, nxt, wid, lane);
#pragma unroll
    for (int i = 0; i < 4; ++i) av[i] = *(const bf16x8*)&cur[abase + (4 + i) * 512];
    __builtin_amdgcn_s_setprio(1);
#pragma unroll
    for (int i = 0; i < 4; ++i)
#pragma unroll
      for (int j = 0; j < 4; ++j)
        acc[4 + i][j] = __builtin_amdgcn_mfma_f32_16x16x32_bf16(av[i], bv[j], acc[4 + i][j], 0, 0, 0);
    __builtin_amdgcn_s_setprio(0);

    asm volatile("s_waitcnt lgkmcnt(0)" ::: "memory");  // this wave's reads of cur retired
    __builtin_amdgcn_s_barrier();                       // before anyone restages over cur
    ++slot; if (slot == 3) slot = 0;
  }
#undef TILE_AB
}

static __device__ __forceinline__ void acc_zero8(f32x4 acc[8][4]) {
#pragma unroll
  for (int i = 0; i < 8; ++i)
#pragma unroll
    for (int j = 0; j < 4; ++j) acc[i][j] = (f32x4){0.f, 0.f, 0.f, 0.f};
}

// C/D frag: col = lane&15, row = quad*4 + t   [verified m89/m91]
static __device__ __forceinline__ void epi_f32(const f32x4 acc[8][4],
                                               float* __restrict__ C, int ldc) {
  const int lane = (int)threadIdx.x & 63, wid = (int)threadIdx.x >> 6;
  const int r = lane & 15, quad = lane >> 4;
  const int wm = wid >> 1, wn = wid & 1;
#pragma unroll
  for (int mi = 0; mi < 8; ++mi) {
    long row = wm * 128 + mi * 16 + quad * 4;
#pragma unroll
    for (int ni = 0; ni < 4; ++ni) {
      long col = wn * 64 + ni * 16 + r;
#pragma unroll
      for (int t = 0; t < 4; ++t) C[(row + t) * ldc + col] = acc[mi][ni][t];
    }
  }
}

static __device__ __forceinline__ void epi_bf16(const f32x4 acc[8][4],
                                                uint16_t* __restrict__ C, int ldc) {
  const int lane = (int)threadIdx.x & 63, wid = (int)threadIdx.x >> 6;
  const int r = lane & 15, quad = lane >> 4;
  const int wm = wid >> 1, wn = wid & 1;
#pragma unroll
  for (int mi = 0; mi < 8; ++mi) {
    long row = wm * 128 + mi * 16 + quad * 4;
#pragma unroll
    for (int ni = 0; ni < 4; ++ni) {
      long col = wn * 64 + ni * 16 + r;
#pragma unroll
      for (int t = 0; t < 4; ++t) C[(row + t) * ldc + col] = f2bf(acc[mi][ni][t]);
    }
  }
}

static __device__ __forceinline__ void epi_split(const f32x4 acc[8][4],
                                                 uint16_t* __restrict__ Ch,
                                                 uint16_t* __restrict__ Cl, int ldc) {
  const int lane = (int)threadIdx.x & 63, wid = (int)threadIdx.x >> 6;
  const int r = lane & 15, quad = lane >> 4;
  const int wm = wid >> 1, wn = wid & 1;
#pragma unroll
  for (int mi = 0; mi < 8; ++mi) {
    long row = wm * 128 + mi * 16 + quad * 4;
#pragma unroll
    for (int ni = 0; ni < 4; ++ni) {
      long col = wn * 64 + ni * 16 + r;
#pragma unroll
      for (int t = 0; t < 4; ++t) {
        float v = acc[mi][ni][t];
        uint16_t hi = f2bf(v);
        Ch[(row + t) * ldc + col] = hi;
        Cl[(row + t) * ldc + col] = f2bf(v - bf2f(hi));
      }
    }
  }
}

// ---------------------------------------------------------------------------
// Merged prep: [0,16384) per-row qp split + Wm GEMV; [16384,28672) q transpose
// (from f32 q directly); [28672,30976) weight transpose/cast.
__global__ __launch_bounds__(256) void prep_all(
    const float* __restrict__ q, const float* __restrict__ p,
    const float* __restrict__ Wc1, const float* __restrict__ Wc2,
    const float* __restrict__ Wb, const float* __restrict__ Wd,
    const float* __restrict__ Wm,
    uint16_t* __restrict__ q_hi, uint16_t* __restrict__ q_lo,
    uint16_t* __restrict__ p_hi, uint16_t* __restrict__ p_lo,
    uint16_t* __restrict__ pd, uint16_t* __restrict__ qT,
    uint16_t* __restrict__ Wc1T, uint16_t* __restrict__ Wc2T,
    uint16_t* __restrict__ WbTh, uint16_t* __restrict__ WbTl,
    float* __restrict__ qWm, float* __restrict__ pWm) {
  __shared__ float smem[32 * 33];
  const int blk = (int)blockIdx.x;
  const int tid = (int)threadIdx.x;
  if (blk < NB * NT) {
    const long base = (long)blk * NH;
    float sq = 0.f, sp = 0.f;
#pragma unroll
    for (int k = 0; k < 3; ++k) {
      int h = tid + 256 * k;
      long idx = base + h;
      float qv = q[idx], pv = p[idx];
      uint16_t qh = f2bf(qv);
      q_hi[idx] = qh; q_lo[idx] = f2bf(qv - bf2f(qh));
      uint16_t ph = f2bf(pv);
      p_hi[idx] = ph; p_lo[idx] = f2bf(pv - bf2f(ph));
      pd[idx] = f2bf(pv * Wd[h]);
      float w = Wm[h];
      sq += qv * w; sp += pv * w;
    }
    for (int o = 32; o; o >>= 1) { sq += __shfl_down(sq, o); sp += __shfl_down(sp, o); }
    int lane = tid & 63, wv = tid >> 6;
    if (lane == 0) { smem[wv] = sq; smem[4 + wv] = sp; }
    __syncthreads();
    if (tid == 0) {
      qWm[blk] = smem[0] + smem[1] + smem[2] + smem[3];
      pWm[blk] = smem[4] + smem[5] + smem[6] + smem[7];
    }
  } else if (blk < NB * NT + 24 * 8 * NB) {
    // qT[b,h,t] = bf16(q[b,t,h]), 32x32 LDS tiles
    int t = blk - NB * NT;
    int ht = t % 24, tt = (t / 24) % 8, b = t / 192;
    int h0 = ht * 32, t0 = tt * 32;
    int tx = tid & 31, ty = tid >> 5;  // ty in [0,8)
    const float* src = q + ((long)b * NT + t0) * NH + h0;
    for (int s = 0; s < 32; s += 8) smem[(ty + s) * 33 + tx] = src[(long)(ty + s) * NH + tx];
    __syncthreads();
    uint16_t* dst = qT + ((long)b * NH + h0) * NT + t0;
    for (int s = 0; s < 32; s += 8) dst[(long)(ty + s) * NT + tx] = f2bf(smem[tx * 33 + ty + s]);
  } else {
    int idx = (blk - (NB * NT + 24 * 8 * NB)) * 256 + tid;
    if (idx < NT * NH) {
      int i = idx / NH, h = idx % NH;
      Wc1T[idx] = f2bf(Wc1[h * NT + i]);
      Wc2T[idx] = f2bf(Wc2[h * NT + i]);
    }
    if (idx < NH * NH) {
      int n = idx / NH, k = idx % NH;
      float w = Wb[k * NH + n];
      uint16_t hi = f2bf(w);
      WbTh[idx] = hi;
      WbTl[idx] = f2bf(w - bf2f(hi));
    }
  }
}

// ---------------------------------------------------------------------------
// Launch A (768 blocks, 256x128 tiles). pwb FIRST for balance: 512 resident
// slots (2/CU) start 384 pwb (72 K-tiles) + 128 fused3 (24); freed slots run
// 3x fused3 = 72 K-tiles -> near-uniform finish.
//   pwb (bid<384): j=xcd-chunk, nt=j/64, b=j%64: pWb[b] cols [nt*128,+128).
//   fused3:        j=xcd-chunk, op=j/128, b=(j%128)>>1, nh=j&1.
__global__ __launch_bounds__(256, 2) void gemm_big3(
    const uint16_t* __restrict__ Wc1T, const uint16_t* __restrict__ Wc2T,
    const uint16_t* __restrict__ q_hi, const uint16_t* __restrict__ p_hi,
    const uint16_t* __restrict__ p_lo, const uint16_t* __restrict__ pd,
    const uint16_t* __restrict__ WbTh, const uint16_t* __restrict__ WbTl,
    uint16_t* __restrict__ whqT, uint16_t* __restrict__ whp,
    uint16_t* __restrict__ sd,
    uint16_t* __restrict__ pWbh, uint16_t* __restrict__ pWbl) {
  __shared__ __align__(16) uint16_t lds[3 * SLOT_U16];
  const long sQP = (long)NT * NH, sTT = (long)NT * NT;
  const int bid = (int)blockIdx.x;
  f32x4 acc[8][4];
  acc_zero8(acc);
  if (bid < 384) {
    const int j = (bid & 7) * 48 + (bid >> 3);   // XCD-chunk; nt-major -> Wb panel/XCD
    const int nt = j / 64, b = j - nt * 64;
    const uint16_t* Ah = p_hi + b * sQP;
    const uint16_t* Al = p_lo + b * sQP;
    const uint16_t* Bh = WbTh + (long)nt * 128 * NH;
    const uint16_t* Bl = WbTl + (long)nt * 128 * NH;
    gemm_core<3, 24>(Ah, Ah, Al, Bh, Bl, Bh, NH, NH, lds, acc);
    epi_split(acc, pWbh + b * sQP + nt * 128, pWbl + b * sQP + nt * 128, NH);
  } else {
    const int f = bid - 384;
    const int j = (f & 7) * 48 + (f >> 3);       // XCD-chunk; op-major -> weight/XCD
    const int op = j / 128, rem = j - op * 128;
    const int b = rem >> 1, nh = rem & 1;
    const uint16_t* A; const uint16_t* B; uint16_t* C;
    if (op == 0)      { A = Wc1T;           B = q_hi + b * sQP + (long)nh * 128 * NH; C = whqT + b * sTT + nh * 128; }
    else if (op == 1) { A = p_hi + b * sQP; B = Wc2T + (long)nh * 128 * NH;           C = whp  + b * sTT + nh * 128; }
    else              { A = pd   + b * sQP; B = q_hi + b * sQP + (long)nh * 128 * NH; C = sd   + b * sTT + nh * 128; }
    gemm_core<1, 24>(A, nullptr, nullptr, B, nullptr, nullptr, NH, NH, lds, acc);
    epi_bf16(acc, C, NT);
  }
}

// sb partials (384 blocks): j = xcd-chunk, pr = j/128, b = (j%128)>>1, nh = j&1.
//   pr0: pWbh x q_hi^T -> sb0 ; pr1: pWbh x q_lo^T -> sb1 ; pr2: pWbl x q_hi^T -> sb2
__global__ __launch_bounds__(256, 2) void gemm_sb(
    const uint16_t* __restrict__ pWbh, const uint16_t* __restrict__ pWbl,
    const uint16_t* __restrict__ q_hi, const uint16_t* __restrict__ q_lo,
    float* __restrict__ sb0, float* __restrict__ sb1, float* __restrict__ sb2) {
  __shared__ __align__(16) uint16_t lds[3 * SLOT_U16];
  const long sQP = (long)NT * NH, sTT = (long)NT * NT;
  const int bid = (int)blockIdx.x;
  const int j = (bid & 7) * 48 + (bid >> 3);
  const int pr = j / 128, rem = j - pr * 128;
  const int b = rem >> 1, nh = rem & 1;
  const uint16_t* A = (pr == 2 ? pWbl : pWbh) + b * sQP;
  const uint16_t* B = (pr == 1 ? q_lo : q_hi) + b * sQP + (long)nh * 128 * NH;
  float* C = (pr == 0 ? sb0 : (pr == 1 ? sb1 : sb2)) + b * sTT + nh * 128;
  f32x4 acc[8][4];
  acc_zero8(acc);
  gemm_core<1, 24>(A, nullptr, nullptr, B, nullptr, nullptr, NH, NH, lds, acc);
  epi_f32(acc, C, NT);
}

// PV (1536 blocks): j = xcd-chunk, a = j/384, b = (j%384)/6, nt = j%6.
// out_a[b] cols [nt*128,+128) = P_a[b] x q[b]  (A = P_a [T,T], B = qT [H,T]).
__global__ __launch_bounds__(256, 2) void gemm_pv(
    const uint16_t* __restrict__ P, const uint16_t* __restrict__ qT,
    float* __restrict__ out) {
  __shared__ __align__(16) uint16_t lds[3 * SLOT_U16];
  const long sQP = (long)NT * NH, sTT = (long)NT * NT;
  const long PB = (long)NB * sTT, nqp = (long)NB * sQP;
  const int bid = (int)blockIdx.x;
  const int j = (bid & 7) * 192 + (bid >> 3);
  const int a = j / 384, rem = j - a * 384;
  const int b = rem / 6, nt = rem - b * 6;
  const uint16_t* A = P + (long)a * PB + b * sTT;
  const uint16_t* B = qT + b * sQP + (long)nt * 128 * NT;
  f32x4 acc[8][4];
  acc_zero8(acc);
  gemm_core<1, 8>(A, nullptr, nullptr, B, nullptr, nullptr, NT, NT, lds, acc);
  epi_f32(acc, out + (long)a * nqp + b * sQP + nt * 128, NH);
}

// ---------------------------------------------------------------------------
// One wave per (b,i) row: assemble 4 score rows, shuffle-reduce softmax, emit bf16 P.
__global__ __launch_bounds__(64) void softmax_k(
    const uint16_t* __restrict__ whp, const uint16_t* __restrict__ whqT,
    const float* __restrict__ sb0, const float* __restrict__ sb1,
    const float* __restrict__ sb2, const uint16_t* __restrict__ sd,
    const float* __restrict__ qWm, const float* __restrict__ pWm,
    const float* __restrict__ vc, const float* __restrict__ vd,
    const float* __restrict__ vm,
    uint16_t* __restrict__ P) {
  int bi = blockIdx.x;  // b*NT + i
  int b = bi >> 8, i = bi & 255;
  int lane = threadIdx.x;
  long rowoff = (long)bi * NT;
  const long PB = (long)NB * NT * NT;
  float vci = vc[i];
  float pwm = pWm[(long)b * NT + i];
  float vals[4][4];
#pragma unroll
  for (int u = 0; u < 4; ++u) {
    int j = lane + 64 * u;
    long off = rowoff + j;
    vals[0][u] = tanhf(bf2f(whp[off]) + bf2f(whqT[off])) * vci;   // vc per-i
    vals[1][u] = sb0[off] + sb1[off] + sb2[off];                   // bilinear hi/lo sum
    vals[2][u] = tanhf(bf2f(sd[off])) * vd[j];                     // vd per-j
    vals[3][u] = tanhf(qWm[(long)b * NT + j] - pwm) * vm[j];       // vm per-j
  }
#pragma unroll
  for (int a = 0; a < 4; ++a) {
    float m = fmaxf(fmaxf(vals[a][0], vals[a][1]), fmaxf(vals[a][2], vals[a][3]));
    for (int o = 32; o; o >>= 1) m = fmaxf(m, __shfl_xor(m, o));
    float e[4], s = 0.f;
#pragma unroll
    for (int u = 0; u < 4; ++u) { e[u] = __expf(vals[a][u] - m); s += e[u]; }
    for (int o = 32; o; o >>= 1) s += __shfl_xor(s, o);
    float inv = 1.f / s;
#pragma unroll
    for (int u = 0; u < 4; ++u)
      P[a * PB + rowoff + lane + 64 * u] = f2bf(e[u] * inv);
  }
}

// ---------------------------------------------------------------------------
extern "C" void kernel_launch(void* const* d_in, const int* in_sizes, int n_in,
                              void* d_out, int out_size, void* d_ws, size_t ws_size,
                              hipStream_t stream) {
  const float* q   = (const float*)d_in[0];
  const float* p   = (const float*)d_in[1];
  const float* Wc1 = (const float*)d_in[2];
  const float* Wc2 = (const float*)d_in[3];
  const float* vc  = (const float*)d_in[4];
  const float* Wb  = (const float*)d_in[5];
  const float* Wd  = (const float*)d_in[6];
  const float* vd  = (const float*)d_in[7];
  const float* Wm  = (const float*)d_in[8];
  const float* vm  = (const float*)d_in[9];
  (void)in_sizes; (void)n_in; (void)out_size; (void)ws_size;

  char* ws = (char*)d_ws;
  size_t o = 0;
  auto alloc = [&](size_t bytes) -> char* {
    char* r = ws + o;
    o = (o + bytes + 255) & ~(size_t)255;
    return r;
  };
  const size_t nqp = (size_t)NB * NT * NH;   // 12.58M
  const size_t ntt = (size_t)NB * NT * NT;   // 4.19M

  uint16_t* Wc1T = (uint16_t*)alloc((size_t)NT * NH * 2);
  uint16_t* Wc2T = (uint16_t*)alloc((size_t)NT * NH * 2);
  uint16_t* WbTh = (uint16_t*)alloc((size_t)NH * NH * 2);
  uint16_t* WbTl = (uint16_t*)alloc((size_t)NH * NH * 2);
  uint16_t* q_hi = (uint16_t*)alloc(nqp * 2);
  uint16_t* q_lo = (uint16_t*)alloc(nqp * 2);
  uint16_t* p_hi = (uint16_t*)alloc(nqp * 2);
  uint16_t* p_lo = (uint16_t*)alloc(nqp * 2);   // dead after gemm_big3 -> reused as sb1
  uint16_t* pd   = (uint16_t*)alloc(nqp * 2);   // dead after gemm_big3 -> reused as sb2
  uint16_t* qT   = (uint16_t*)alloc(nqp * 2);
  float*    qWmB = (float*)alloc((size_t)NB * NT * 4);
  float*    pWmB = (float*)alloc((size_t)NB * NT * 4);
  uint16_t* whp  = (uint16_t*)alloc(ntt * 2);
  uint16_t* whqT = (uint16_t*)alloc(ntt * 2);
  uint16_t* pWbh = (uint16_t*)alloc(nqp * 2);
  uint16_t* pWbl = (uint16_t*)alloc(nqp * 2);
  float*    sb0  = (float*)alloc(ntt * 4);
  uint16_t* sd   = (uint16_t*)alloc(ntt * 2);
  uint16_t* P    = (uint16_t*)alloc(4 * ntt * 2);

  // sb partials alias buffers dead by the time gemm_sb runs.
  float* sb1 = (float*)p_lo;
  float* sb2 = (float*)pd;

  prep_all<<<dim3(NB * NT + 24 * 8 * NB + (NH * NH + 255) / 256), dim3(256), 0, stream>>>(
      q, p, Wc1, Wc2, Wb, Wd, Wm,
      q_hi, q_lo, p_hi, p_lo, pd, qT, Wc1T, Wc2T, WbTh, WbTl, qWmB, pWmB);

  gemm_big3<<<dim3(768), dim3(256), 0, stream>>>(
      Wc1T, Wc2T, q_hi, p_hi, p_lo, pd, WbTh, WbTl,
      whqT, whp, sd, pWbh, pWbl);

  gemm_sb<<<dim3(384), dim3(256), 0, stream>>>(
      pWbh, pWbl, q_hi, q_lo, sb0, sb1, sb2);

  softmax_k<<<dim3(NB * NT), dim3(64), 0, stream>>>(
      whp, whqT, sb0, sb1, sb2, sd, qWmB, pWmB, vc, vd, vm, P);

  gemm_pv<<<dim3(1536), dim3(256), 0, stream>>>(P, qT, (float*)d_out);
}

// Round 4
// 518.699 us; speedup vs baseline: 1.3504x; 1.0481x over previous
//
#include <hip/hip_runtime.h>
#include <hip/hip_bf16.h>
#include <stdint.h>

#define NB 64
#define NT 256
#define NH 768

typedef float f32x4 __attribute__((ext_vector_type(4)));
typedef __bf16 bf16x8 __attribute__((ext_vector_type(8)));

static __device__ __forceinline__ uint16_t f2bf(float f) {
  union { float f; uint32_t u; } v; v.f = f;
  uint32_t r = v.u + 0x7FFFu + ((v.u >> 16) & 1u);
  return (uint16_t)(r >> 16);
}
static __device__ __forceinline__ float bf2f(uint16_t h) {
  union { uint32_t u; float f; } v; v.u = ((uint32_t)h) << 16;
  return v.f;
}

// global -> LDS direct DMA, 16B per lane. LDS dest = wave-uniform base + lane*16.
typedef const __attribute__((address_space(1))) uint32_t* gp1_t;
typedef __attribute__((address_space(3))) uint32_t* lp3_t;
static __device__ __forceinline__ void gload_lds16(const uint16_t* g, uint16_t* l) {
  __builtin_amdgcn_global_load_lds((gp1_t)g, (lp3_t)l, 16, 0, 0);
}

// ---------------------------------------------------------------------------
// 256x128 pipelined GEMM core: C += A(256,K) * B(128,K)^T.
// 4 waves (2m x 2n), per-wave 128x64 output = acc[8][4] f32x4 (AGPRs).
// BK=32, 3 rolling LDS slots of 24 KB (A 16K + B 8K), stage tile kt+2 while
// computing kt; counted vmcnt(9/6/0); 2 barriers per K-tile; fragments read
// ONCE per K-tile (av[8] + bv[4] = 12 b128/wave). LDS XOR-swizzle
// k^=((row>>3)&1)<<4 elems applied as pre-swizzled global source (linear
// gload_lds dest) + swizzled read.
// INTER=true: product index cycles FASTEST (t -> kt=t/NPROD, pr=t%NPROD) so
// a re-staged A K-tile is an L2 hit (fetched one superstep earlier).
#define SLOT_U16 12288

// Stage parts [P0,P1) of one K-tile. Part 0..3 = A rows part*64..; 4..5 = B rows.
template <int P0, int P1>
static __device__ __forceinline__ void stageN(
    const uint16_t* __restrict__ Ap, const uint16_t* __restrict__ Bp,
    int k0, int lda, int ldb, uint16_t* __restrict__ slot, int wid, int lane) {
#pragma unroll
  for (int part = P0; part < P1; ++part) {
    const bool isB = part >= 4;
    const int row = (isB ? (part - 4) : part) * 64 + wid * 16 + (lane >> 2);
    const int kcol = ((lane & 3) * 8) ^ (((lane >> 5) & 1) << 4);  // inverse swizzle at source
    const uint16_t* src = (isB ? Bp + (long)row * ldb : Ap + (long)row * lda) + k0 + kcol;
    gload_lds16(src, slot + part * 2048 + wid * 512);
  }
}

template <int NPROD, int NKPER, bool INTER = false>
static __device__ __forceinline__ void gemm_core(
    const uint16_t* __restrict__ A0, const uint16_t* __restrict__ A1,
    const uint16_t* __restrict__ A2,
    const uint16_t* __restrict__ B0, const uint16_t* __restrict__ B1,
    const uint16_t* __restrict__ B2,
    int lda, int ldb, uint16_t* __restrict__ lds, f32x4 acc[8][4]) {
  const int tid = (int)threadIdx.x;
  const int wid = tid >> 6, lane = tid & 63;
  const int r = lane & 15, quad = lane >> 4;
  const int wm = wid >> 1, wn = wid & 1;
  const int ks = (quad * 8) ^ ((r >> 3) << 4);          // swizzled k-slot (u16 units)
  const int abase = (wm * 128 + r) * 32 + ks;           // + frag*512
  const int bbase = 8192 + (wn * 64 + r) * 32 + ks;     // + frag*512
  constexpr int nk = NPROD * NKPER;

#define TILE_AB(t, Ap, Bp, k0)                                      \
  {                                                                 \
    int pr_ = 0, kk_ = (t);                                         \
    if (NPROD > 1) {                                                \
      if (INTER) { kk_ = (t) / NPROD; pr_ = (t) - kk_ * NPROD; }    \
      else       { pr_ = (t) / NKPER; kk_ = (t) - pr_ * NKPER; }    \
    }                                                               \
    Ap = pr_ == 0 ? A0 : (pr_ == 1 ? A1 : A2);                      \
    Bp = pr_ == 0 ? B0 : (pr_ == 1 ? B1 : B2);                      \
    k0 = kk_ * 32;                                                  \
  }

  // Prologue: fully stage tiles 0 (slot0) and 1 (slot1): 12 loads/wave in flight.
  {
    const uint16_t* Ap; const uint16_t* Bp; int k0;
    TILE_AB(0, Ap, Bp, k0);
    stageN<0, 6>(Ap, Bp, k0, lda, ldb, lds, wid, lane);
    TILE_AB(1, Ap, Bp, k0);
    stageN<0, 6>(Ap, Bp, k0, lda, ldb, lds + SLOT_U16, wid, lane);
  }

  int slot = 0;
  for (int kt = 0; kt < nk; ++kt) {
    uint16_t* cur = lds + slot * SLOT_U16;
    int ns = slot + 2; if (ns >= 3) ns -= 3;
    uint16_t* nxt = lds + ns * SLOT_U16;  // read finished at iter kt-1's end barrier
    const uint16_t* An = A0; const uint16_t* Bn = B0; int k0n = 0;
    const bool more2 = (kt + 2 < nk), more1 = (kt + 1 < nk);
    if (more2) TILE_AB(kt + 2, An, Bn, k0n);

    // ---- phase 0: stage A-half of kt+2, sync tile kt, compute m-rows 0..63
    if (more2) stageN<0, 3>(An, Bn, k0n, lda, ldb, nxt, wid, lane);
    // Outstanding: kt's 6 + kt+1's 6 + 3 just issued = 15; wait to 9 retires
    // exactly tile kt's 6 (vmcnt retires in order).
    if (more2)      asm volatile("s_waitcnt vmcnt(9)" ::: "memory");
    else if (more1) asm volatile("s_waitcnt vmcnt(6)" ::: "memory");
    else            asm volatile("s_waitcnt vmcnt(0)" ::: "memory");
    __builtin_amdgcn_s_barrier();  // all waves' tile-kt loads landed

    bf16x8 av[4], bv[4];
#pragma unroll
    for (int i = 0; i < 4; ++i) av[i] = *(const bf16x8*)&cur[abase + i * 512];
#pragma unroll
    for (int j = 0; j < 4; ++j) bv[j] = *(const bf16x8*)&cur[bbase + j * 512];
    __builtin_amdgcn_s_setprio(1);
#pragma unroll
    for (int i = 0; i < 4; ++i)
#pragma unroll
      for (int j = 0; j < 4; ++j)
        acc[i][j] = __builtin_amdgcn_mfma_f32_16x16x32_bf16(av[i], bv[j], acc[i][j], 0, 0, 0);
    __builtin_amdgcn_s_setprio(0);

    // ---- phase 1: stage B-half of kt+2, compute m-rows 64..127 (bv reused)
    if (more2) stageN<3, 6>(An, Bn, k0n, lda, ldb, nxt, wid, lane);
#pragma unroll
    for (int i = 0; i < 4; ++i) av[i] = *(const bf16x8*)&cur[abase + (4 + i) * 512];
    __builtin_amdgcn_s_setprio(1);
#pragma unroll
    for (int i = 0; i < 4; ++i)
#pragma unroll
      for (int j = 0; j < 4; ++j)
        acc[4 + i][j] = __builtin_amdgcn_mfma_f32_16x16x32_bf16(av[i], bv[j], acc[4 + i][j], 0, 0, 0);
    __builtin_amdgcn_s_setprio(0);

    asm volatile("s_waitcnt lgkmcnt(0)" ::: "memory");  // this wave's reads of cur retired
    __builtin_amdgcn_s_barrier();                       // before anyone restages over cur
    ++slot; if (slot == 3) slot = 0;
  }
#undef TILE_AB
}

static __device__ __forceinline__ void acc_zero8(f32x4 acc[8][4]) {
#pragma unroll
  for (int i = 0; i < 8; ++i)
#pragma unroll
    for (int j = 0; j < 4; ++j) acc[i][j] = (f32x4){0.f, 0.f, 0.f, 0.f};
}

// C/D frag: col = lane&15, row = quad*4 + t   [verified m89/m91]
static __device__ __forceinline__ void epi_f32(const f32x4 acc[8][4],
                                               float* __restrict__ C, int ldc) {
  const int lane = (int)threadIdx.x & 63, wid = (int)threadIdx.x >> 6;
  const int r = lane & 15, quad = lane >> 4;
  const int wm = wid >> 1, wn = wid & 1;
#pragma unroll
  for (int mi = 0; mi < 8; ++mi) {
    long row = wm * 128 + mi * 16 + quad * 4;
#pragma unroll
    for (int ni = 0; ni < 4; ++ni) {
      long col = wn * 64 + ni * 16 + r;
#pragma unroll
      for (int t = 0; t < 4; ++t) C[(row + t) * ldc + col] = acc[mi][ni][t];
    }
  }
}

static __device__ __forceinline__ void epi_bf16(const f32x4 acc[8][4],
                                                uint16_t* __restrict__ C, int ldc) {
  const int lane = (int)threadIdx.x & 63, wid = (int)threadIdx.x >> 6;
  const int r = lane & 15, quad = lane >> 4;
  const int wm = wid >> 1, wn = wid & 1;
#pragma unroll
  for (int mi = 0; mi < 8; ++mi) {
    long row = wm * 128 + mi * 16 + quad * 4;
#pragma unroll
    for (int ni = 0; ni < 4; ++ni) {
      long col = wn * 64 + ni * 16 + r;
#pragma unroll
      for (int t = 0; t < 4; ++t) C[(row + t) * ldc + col] = f2bf(acc[mi][ni][t]);
    }
  }
}

static __device__ __forceinline__ void epi_split(const f32x4 acc[8][4],
                                                 uint16_t* __restrict__ Ch,
                                                 uint16_t* __restrict__ Cl, int ldc) {
  const int lane = (int)threadIdx.x & 63, wid = (int)threadIdx.x >> 6;
  const int r = lane & 15, quad = lane >> 4;
  const int wm = wid >> 1, wn = wid & 1;
#pragma unroll
  for (int mi = 0; mi < 8; ++mi) {
    long row = wm * 128 + mi * 16 + quad * 4;
#pragma unroll
    for (int ni = 0; ni < 4; ++ni) {
      long col = wn * 64 + ni * 16 + r;
#pragma unroll
      for (int t = 0; t < 4; ++t) {
        float v = acc[mi][ni][t];
        uint16_t hi = f2bf(v);
        Ch[(row + t) * ldc + col] = hi;
        Cl[(row + t) * ldc + col] = f2bf(v - bf2f(hi));
      }
    }
  }
}

// ---------------------------------------------------------------------------
// Merged prep: [0,16384) per-row qp split + Wm GEMV; [16384,28672) q transpose
// (from f32 q directly); [28672,30976) weight transpose/cast.
__global__ __launch_bounds__(256) void prep_all(
    const float* __restrict__ q, const float* __restrict__ p,
    const float* __restrict__ Wc1, const float* __restrict__ Wc2,
    const float* __restrict__ Wb, const float* __restrict__ Wd,
    const float* __restrict__ Wm,
    uint16_t* __restrict__ q_hi, uint16_t* __restrict__ q_lo,
    uint16_t* __restrict__ p_hi, uint16_t* __restrict__ p_lo,
    uint16_t* __restrict__ pd, uint16_t* __restrict__ qT,
    uint16_t* __restrict__ Wc1T, uint16_t* __restrict__ Wc2T,
    uint16_t* __restrict__ WbTh, uint16_t* __restrict__ WbTl,
    float* __restrict__ qWm, float* __restrict__ pWm) {
  __shared__ float smem[32 * 33];
  const int blk = (int)blockIdx.x;
  const int tid = (int)threadIdx.x;
  if (blk < NB * NT) {
    const long base = (long)blk * NH;
    float sq = 0.f, sp = 0.f;
#pragma unroll
    for (int k = 0; k < 3; ++k) {
      int h = tid + 256 * k;
      long idx = base + h;
      float qv = q[idx], pv = p[idx];
      uint16_t qh = f2bf(qv);
      q_hi[idx] = qh; q_lo[idx] = f2bf(qv - bf2f(qh));
      uint16_t ph = f2bf(pv);
      p_hi[idx] = ph; p_lo[idx] = f2bf(pv - bf2f(ph));
      pd[idx] = f2bf(pv * Wd[h]);
      float w = Wm[h];
      sq += qv * w; sp += pv * w;
    }
    for (int o = 32; o; o >>= 1) { sq += __shfl_down(sq, o); sp += __shfl_down(sp, o); }
    int lane = tid & 63, wv = tid >> 6;
    if (lane == 0) { smem[wv] = sq; smem[4 + wv] = sp; }
    __syncthreads();
    if (tid == 0) {
      qWm[blk] = smem[0] + smem[1] + smem[2] + smem[3];
      pWm[blk] = smem[4] + smem[5] + smem[6] + smem[7];
    }
  } else if (blk < NB * NT + 24 * 8 * NB) {
    // qT[b,h,t] = bf16(q[b,t,h]), 32x32 LDS tiles
    int t = blk - NB * NT;
    int ht = t % 24, tt = (t / 24) % 8, b = t / 192;
    int h0 = ht * 32, t0 = tt * 32;
    int tx = tid & 31, ty = tid >> 5;  // ty in [0,8)
    const float* src = q + ((long)b * NT + t0) * NH + h0;
    for (int s = 0; s < 32; s += 8) smem[(ty + s) * 33 + tx] = src[(long)(ty + s) * NH + tx];
    __syncthreads();
    uint16_t* dst = qT + ((long)b * NH + h0) * NT + t0;
    for (int s = 0; s < 32; s += 8) dst[(long)(ty + s) * NT + tx] = f2bf(smem[tx * 33 + ty + s]);
  } else {
    int idx = (blk - (NB * NT + 24 * 8 * NB)) * 256 + tid;
    if (idx < NT * NH) {
      int i = idx / NH, h = idx % NH;
      Wc1T[idx] = f2bf(Wc1[h * NT + i]);
      Wc2T[idx] = f2bf(Wc2[h * NT + i]);
    }
    if (idx < NH * NH) {
      int n = idx / NH, k = idx % NH;
      float w = Wb[k * NH + n];
      uint16_t hi = f2bf(w);
      WbTh[idx] = hi;
      WbTl[idx] = f2bf(w - bf2f(hi));
    }
  }
}

// ---------------------------------------------------------------------------
// Launch A (768 blocks, 256x128 tiles). bids [0,384) = pwb (72 K-tiles),
// [384,768) = fused3 (24 K-tiles). XCD chunking is b-MAJOR: each XCD owns 8
// consecutive batches and ALL tiles/products for them -> the big per-batch
// operand panels (p, q, pd) are fetched from HBM once per XCD and L2-shared.
//   pwb:    jp = b*6 + nt          (6 nt-blocks share p_hi/p_lo[b])
//   fused3: jf = b*6 + op*2 + nh   (op0,op2 share q_hi[b]; op1 shares p_hi[b])
// pwb uses INTER product order: per kt (Ah,Bh),(Ah,Bl),(Al,Bh) -> Ah restage
// is an immediate L2 hit.
__global__ __launch_bounds__(256, 2) void gemm_big3(
    const uint16_t* __restrict__ Wc1T, const uint16_t* __restrict__ Wc2T,
    const uint16_t* __restrict__ q_hi, const uint16_t* __restrict__ p_hi,
    const uint16_t* __restrict__ p_lo, const uint16_t* __restrict__ pd,
    const uint16_t* __restrict__ WbTh, const uint16_t* __restrict__ WbTl,
    uint16_t* __restrict__ whqT, uint16_t* __restrict__ whp,
    uint16_t* __restrict__ sd,
    uint16_t* __restrict__ pWbh, uint16_t* __restrict__ pWbl) {
  __shared__ __align__(16) uint16_t lds[3 * SLOT_U16];
  const long sQP = (long)NT * NH, sTT = (long)NT * NT;
  const int bid = (int)blockIdx.x;
  f32x4 acc[8][4];
  acc_zero8(acc);
  if (bid < 384) {
    const int j = (bid & 7) * 48 + (bid >> 3);   // b-major: XCD x owns b in [x*8,x*8+8)
    const int b = j / 6, nt = j - b * 6;
    const uint16_t* Ah = p_hi + b * sQP;
    const uint16_t* Al = p_lo + b * sQP;
    const uint16_t* Bh = WbTh + (long)nt * 128 * NH;
    const uint16_t* Bl = WbTl + (long)nt * 128 * NH;
    gemm_core<3, 24, true>(Ah, Ah, Al, Bh, Bl, Bh, NH, NH, lds, acc);
    epi_split(acc, pWbh + b * sQP + nt * 128, pWbl + b * sQP + nt * 128, NH);
  } else {
    const int f = bid - 384;
    const int j = (f & 7) * 48 + (f >> 3);       // b-major
    const int b = j / 6, rem = j - b * 6;
    const int op = rem >> 1, nh = rem & 1;
    const uint16_t* A; const uint16_t* B; uint16_t* C;
    if (op == 0)      { A = Wc1T;           B = q_hi + b * sQP + (long)nh * 128 * NH; C = whqT + b * sTT + nh * 128; }
    else if (op == 1) { A = p_hi + b * sQP; B = Wc2T + (long)nh * 128 * NH;           C = whp  + b * sTT + nh * 128; }
    else              { A = pd   + b * sQP; B = q_hi + b * sQP + (long)nh * 128 * NH; C = sd   + b * sTT + nh * 128; }
    gemm_core<1, 24>(A, nullptr, nullptr, B, nullptr, nullptr, NH, NH, lds, acc);
    epi_bf16(acc, C, NT);
  }
}

// sb partials (384 blocks, b-major XCD): j = b*6 + pr*2 + nh.
//   pr0: pWbh x q_hi^T -> sb0 ; pr1: pWbh x q_lo^T -> sb1 ; pr2: pWbl x q_hi^T -> sb2
// Blocks of one b share pWbh (pr0,pr1), q_hi (pr0,pr2) in their XCD's L2.
__global__ __launch_bounds__(256, 2) void gemm_sb(
    const uint16_t* __restrict__ pWbh, const uint16_t* __restrict__ pWbl,
    const uint16_t* __restrict__ q_hi, const uint16_t* __restrict__ q_lo,
    float* __restrict__ sb0, float* __restrict__ sb1, float* __restrict__ sb2) {
  __shared__ __align__(16) uint16_t lds[3 * SLOT_U16];
  const long sQP = (long)NT * NH, sTT = (long)NT * NT;
  const int bid = (int)blockIdx.x;
  const int j = (bid & 7) * 48 + (bid >> 3);
  const int b = j / 6, rem = j - b * 6;
  const int pr = rem >> 1, nh = rem & 1;
  const uint16_t* A = (pr == 2 ? pWbl : pWbh) + b * sQP;
  const uint16_t* B = (pr == 1 ? q_lo : q_hi) + b * sQP + (long)nh * 128 * NH;
  float* C = (pr == 0 ? sb0 : (pr == 1 ? sb1 : sb2)) + b * sTT + nh * 128;
  f32x4 acc[8][4];
  acc_zero8(acc);
  gemm_core<1, 24>(A, nullptr, nullptr, B, nullptr, nullptr, NH, NH, lds, acc);
  epi_f32(acc, C, NT);
}

// PV (1536 blocks, b-major XCD): j = b*24 + a*6 + nt.
// Per XCD: 8 batches; qT[b] shared by 24 blocks, P_a[b] by 6.
// out_a[b] cols [nt*128,+128) = P_a[b] x q[b]  (A = P_a [T,T], B = qT [H,T]).
__global__ __launch_bounds__(256, 2) void gemm_pv(
    const uint16_t* __restrict__ P, const uint16_t* __restrict__ qT,
    float* __restrict__ out) {
  __shared__ __align__(16) uint16_t lds[3 * SLOT_U16];
  const long sQP = (long)NT * NH, sTT = (long)NT * NT;
  const long PB = (long)NB * sTT, nqp = (long)NB * sQP;
  const int bid = (int)blockIdx.x;
  const int j = (bid & 7) * 192 + (bid >> 3);
  const int b = j / 24, rem = j - b * 24;
  const int a = rem / 6, nt = rem - a * 6;
  const uint16_t* A = P + (long)a * PB + b * sTT;
  const uint16_t* B = qT + b * sQP + (long)nt * 128 * NT;
  f32x4 acc[8][4];
  acc_zero8(acc);
  gemm_core<1, 8>(A, nullptr, nullptr, B, nullptr, nullptr, NT, NT, lds, acc);
  epi_f32(acc, out + (long)a * nqp + b * sQP + nt * 128, NH);
}

// ---------------------------------------------------------------------------
// One wave per (b,i) row: assemble 4 score rows, shuffle-reduce softmax, emit bf16 P.
__global__ __launch_bounds__(64) void softmax_k(
    const uint16_t* __restrict__ whp, const uint16_t* __restrict__ whqT,
    const float* __restrict__ sb0, const float* __restrict__ sb1,
    const float* __restrict__ sb2, const uint16_t* __restrict__ sd,
    const float* __restrict__ qWm, const float* __restrict__ pWm,
    const float* __restrict__ vc, const float* __restrict__ vd,
    const float* __restrict__ vm,
    uint16_t* __restrict__ P) {
  int bi = blockIdx.x;  // b*NT + i
  int b = bi >> 8, i = bi & 255;
  int lane = threadIdx.x;
  long rowoff = (long)bi * NT;
  const long PB = (long)NB * NT * NT;
  float vci = vc[i];
  float pwm = pWm[(long)b * NT + i];
  float vals[4][4];
#pragma unroll
  for (int u = 0; u < 4; ++u) {
    int j = lane + 64 * u;
    long off = rowoff + j;
    vals[0][u] = tanhf(bf2f(whp[off]) + bf2f(whqT[off])) * vci;   // vc per-i
    vals[1][u] = sb0[off] + sb1[off] + sb2[off];                   // bilinear hi/lo sum
    vals[2][u] = tanhf(bf2f(sd[off])) * vd[j];                     // vd per-j
    vals[3][u] = tanhf(qWm[(long)b * NT + j] - pwm) * vm[j];       // vm per-j
  }
#pragma unroll
  for (int a = 0; a < 4; ++a) {
    float m = fmaxf(fmaxf(vals[a][0], vals[a][1]), fmaxf(vals[a][2], vals[a][3]));
    for (int o = 32; o; o >>= 1) m = fmaxf(m, __shfl_xor(m, o));
    float e[4], s = 0.f;
#pragma unroll
    for (int u = 0; u < 4; ++u) { e[u] = __expf(vals[a][u] - m); s += e[u]; }
    for (int o = 32; o; o >>= 1) s += __shfl_xor(s, o);
    float inv = 1.f / s;
#pragma unroll
    for (int u = 0; u < 4; ++u)
      P[a * PB + rowoff + lane + 64 * u] = f2bf(e[u] * inv);
  }
}

// ---------------------------------------------------------------------------
extern "C" void kernel_launch(void* const* d_in, const int* in_sizes, int n_in,
                              void* d_out, int out_size, void* d_ws, size_t ws_size,
                              hipStream_t stream) {
  const float* q   = (const float*)d_in[0];
  const float* p   = (const float*)d_in[1];
  const float* Wc1 = (const float*)d_in[2];
  const float* Wc2 = (const float*)d_in[3];
  const float* vc  = (const float*)d_in[4];
  const float* Wb  = (const float*)d_in[5];
  const float* Wd  = (const float*)d_in[6];
  const float* vd  = (const float*)d_in[7];
  const float* Wm  = (const float*)d_in[8];
  const float* vm  = (const float*)d_in[9];
  (void)in_sizes; (void)n_in; (void)out_size; (void)ws_size;

  char* ws = (char*)d_ws;
  size_t o = 0;
  auto alloc = [&](size_t bytes) -> char* {
    char* r = ws + o;
    o = (o + bytes + 255) & ~(size_t)255;
    return r;
  };
  const size_t nqp = (size_t)NB * NT * NH;   // 12.58M
  const size_t ntt = (size_t)NB * NT * NT;   // 4.19M

  uint16_t* Wc1T = (uint16_t*)alloc((size_t)NT * NH * 2);
  uint16_t* Wc2T = (uint16_t*)alloc((size_t)NT * NH * 2);
  uint16_t* WbTh = (uint16_t*)alloc((size_t)NH * NH * 2);
  uint16_t* WbTl = (uint16_t*)alloc((size_t)NH * NH * 2);
  uint16_t* q_hi = (uint16_t*)alloc(nqp * 2);
  uint16_t* q_lo = (uint16_t*)alloc(nqp * 2);
  uint16_t* p_hi = (uint16_t*)alloc(nqp * 2);
  uint16_t* p_lo = (uint16_t*)alloc(nqp * 2);   // dead after gemm_big3 -> reused as sb1
  uint16_t* pd   = (uint16_t*)alloc(nqp * 2);   // dead after gemm_big3 -> reused as sb2
  uint16_t* qT   = (uint16_t*)alloc(nqp * 2);
  float*    qWmB = (float*)alloc((size_t)NB * NT * 4);
  float*    pWmB = (float*)alloc((size_t)NB * NT * 4);
  uint16_t* whp  = (uint16_t*)alloc(ntt * 2);
  uint16_t* whqT = (uint16_t*)alloc(ntt * 2);
  uint16_t* pWbh = (uint16_t*)alloc(nqp * 2);
  uint16_t* pWbl = (uint16_t*)alloc(nqp * 2);
  float*    sb0  = (float*)alloc(ntt * 4);
  uint16_t* sd   = (uint16_t*)alloc(ntt * 2);
  uint16_t* P    = (uint16_t*)alloc(4 * ntt * 2);

  // sb partials alias buffers dead by the time gemm_sb runs.
  float* sb1 = (float*)p_lo;
  float* sb2 = (float*)pd;

  prep_all<<<dim3(NB * NT + 24 * 8 * NB + (NH * NH + 255) / 256), dim3(256), 0, stream>>>(
      q, p, Wc1, Wc2, Wb, Wd, Wm,
      q_hi, q_lo, p_hi, p_lo, pd, qT, Wc1T, Wc2T, WbTh, WbTl, qWmB, pWmB);

  gemm_big3<<<dim3(768), dim3(256), 0, stream>>>(
      Wc1T, Wc2T, q_hi, p_hi, p_lo, pd, WbTh, WbTl,
      whqT, whp, sd, pWbh, pWbl);

  gemm_sb<<<dim3(384), dim3(256), 0, stream>>>(
      pWbh, pWbl, q_hi, q_lo, sb0, sb1, sb2);

  softmax_k<<<dim3(NB * NT), dim3(64), 0, stream>>>(
      whp, whqT, sb0, sb1, sb2, sd, qWmB, pWmB, vc, vd, vm, P);

  gemm_pv<<<dim3(1536), dim3(256), 0, stream>>>(P, qT, (float*)d_out);
}